// Round 12
// baseline (174.963 us; speedup 1.0000x reference)
//
#include <hip/hip_runtime.h>
#include <stdint.h>

#define E_DIM 1024
#define N_HEADS 16
#define HEAD_D 64
#define BATCH 2
#define SEQ 2048
#define M_ROWS (BATCH*SEQ)   // 4096

typedef __attribute__((ext_vector_type(8))) short short8;
typedef __attribute__((ext_vector_type(4))) short short4_t;
typedef __attribute__((ext_vector_type(4))) float f32x4;
typedef __attribute__((ext_vector_type(4))) int i32x4;
typedef __attribute__((ext_vector_type(2))) int i32x2;

__device__ __forceinline__ unsigned short f2bf(float f) {
  uint32_t u = __float_as_uint(f);
  u += 0x7FFFu + ((u >> 16) & 1u);   // RTNE
  return (unsigned short)(u >> 16);
}

// async global->LDS, 16B per lane; LDS dest = wave-uniform base + lane*16
__device__ __forceinline__ void gload_lds16(const void* g, void* l) {
  __builtin_amdgcn_global_load_lds(
      (const __attribute__((address_space(1))) uint32_t*)(uintptr_t)g,
      (__attribute__((address_space(3))) uint32_t*)(uint32_t)(uintptr_t)l,
      16, 0, 0);
}

__device__ __forceinline__ int cvtpk(float lo, float hi) {
  int r;
  asm("v_cvt_pk_bf16_f32 %0, %1, %2" : "=v"(r) : "v"(lo), "v"(hi));
  return r;
}

__device__ __forceinline__ void cvt_body(const float* __restrict__ src,
                                         unsigned short* __restrict__ dst, int i) {
  f32x4 a = ((const f32x4*)src)[2*i];
  f32x4 b = ((const f32x4*)src)[2*i + 1];
  union { unsigned short us[8]; i32x4 v; } o;
  o.us[0] = f2bf(a[0]); o.us[1] = f2bf(a[1]);
  o.us[2] = f2bf(a[2]); o.us[3] = f2bf(a[3]);
  o.us[4] = f2bf(b[0]); o.us[5] = f2bf(b[1]);
  o.us[6] = f2bf(b[2]); o.us[7] = f2bf(b[3]);
  ((i32x4*)dst)[i] = o.v;
}

// 3 equal-size f32->bf16 converts in one launch (blockIdx.y selects)
__global__ void cvt3_f32_bf16(const float* __restrict__ s0, const float* __restrict__ s1,
                              const float* __restrict__ s2,
                              unsigned short* __restrict__ d0, unsigned short* __restrict__ d1,
                              unsigned short* __restrict__ d2, int n8) {
  int i = blockIdx.x * blockDim.x + threadIdx.x;
  if (i >= n8) return;
  const float* s = (blockIdx.y == 0) ? s0 : (blockIdx.y == 1) ? s1 : s2;
  unsigned short* d = (blockIdx.y == 0) ? d0 : (blockIdx.y == 1) ? d1 : d2;
  cvt_body(s, d, i);
}

// 4 equal-size f32->bf16 converts in one launch
__global__ void cvt4_f32_bf16(const float* __restrict__ s0, const float* __restrict__ s1,
                              const float* __restrict__ s2, const float* __restrict__ s3,
                              unsigned short* __restrict__ d0, unsigned short* __restrict__ d1,
                              unsigned short* __restrict__ d2, unsigned short* __restrict__ d3,
                              int n8) {
  int i = blockIdx.x * blockDim.x + threadIdx.x;
  if (i >= n8) return;
  const float* s = (blockIdx.y == 0) ? s0 : (blockIdx.y == 1) ? s1
                 : (blockIdx.y == 2) ? s2 : s3;
  unsigned short* d = (blockIdx.y == 0) ? d0 : (blockIdx.y == 1) ? d1
                    : (blockIdx.y == 2) ? d2 : d3;
  cvt_body(s, d, i);
}

// ---------------------------------------------------------------------------
// GEMM body (R8/R9/R10-verified): C[m][n]=(sum_k A[m][k]*B[n][k]+bias[n])*scale
// 128x64 tile / 256 threads, single-barrier double-buffer, N=K=E_DIM fixed.
// ---------------------------------------------------------------------------
template<int OUT_BF16>
__device__ __forceinline__ void gemm_body(const unsigned short* __restrict__ A,
                                          const unsigned short* __restrict__ Bm,
                                          const float* __restrict__ bias,
                                          void* __restrict__ Cout,
                                          float scale, int bx, int by) {
  constexpr int BM = 128, BN = 64, BK = 64, K = E_DIM, N = E_DIM;
  __shared__ __attribute__((aligned(16))) unsigned short Al[2][BM*BK];  // 16KB x2
  __shared__ __attribute__((aligned(16))) unsigned short Bl[2][BN*BK];  //  8KB x2
  const int tid  = threadIdx.x;
  const int lane = tid & 63, w = tid >> 6;
  const int wm = w >> 1, wn = w & 1;          // wave tile 64x32
  const int l15 = lane & 15, l4 = lane >> 4, l7 = lane & 7;
  const int m0 = by * BM, n0 = bx * BN;
  const int jr = lane >> 3, jc = lane & 7;
  const int kcg = jc ^ jr;                    // inverse-swizzled source chunk

#define GSTAGE(KT, BUF)                                                        \
  do {                                                                         \
    _Pragma("unroll")                                                          \
    for (int t = 0; t < 4; ++t) {            /* A: 16 issues of 1KB, 4/wave */ \
      int ia = w*4 + t;                                                        \
      const char* src = (const char*)A +                                       \
          ((size_t)(m0 + ia*8 + jr)*K + (KT))*2 + (kcg << 4);                  \
      gload_lds16(src, (char*)Al[BUF] + ia*1024);                              \
    }                                                                          \
    _Pragma("unroll")                                                          \
    for (int t = 0; t < 2; ++t) {            /* B: 8 issues, 2/wave */         \
      int ib = w*2 + t;                                                        \
      const char* src = (const char*)Bm +                                      \
          ((size_t)(n0 + ib*8 + jr)*K + (KT))*2 + (kcg << 4);                  \
      gload_lds16(src, (char*)Bl[BUF] + ib*1024);                              \
    }                                                                          \
  } while (0)

  f32x4 zero = {0.f, 0.f, 0.f, 0.f};
  f32x4 acc[4][2];
  for (int i = 0; i < 4; ++i) for (int j = 0; j < 2; ++j) acc[i][j] = zero;

  GSTAGE(0, 0);
  __syncthreads();

  int cur = 0;
  const int NKT = K / BK;
  for (int kt = 0; kt < NKT; ++kt) {
    if (kt + 1 < NKT) GSTAGE((kt + 1) * BK, cur ^ 1);

#pragma unroll
    for (int ks = 0; ks < 2; ++ks) {
      const int sw = ((ks*4 + l4) ^ l7) << 4;
      short8 af[4], bf[2];
#pragma unroll
      for (int mf = 0; mf < 4; ++mf)
        af[mf] = *(const short8*)((const char*)Al[cur] + (wm*64 + mf*16 + l15)*128 + sw);
#pragma unroll
      for (int nf = 0; nf < 2; ++nf)
        bf[nf] = *(const short8*)((const char*)Bl[cur] + (wn*32 + nf*16 + l15)*128 + sw);
#pragma unroll
      for (int mf = 0; mf < 4; ++mf)
#pragma unroll
        for (int nf = 0; nf < 2; ++nf)
          acc[mf][nf] = __builtin_amdgcn_mfma_f32_16x16x32_bf16(
              af[mf], bf[nf], acc[mf][nf], 0, 0, 0);
    }

    __syncthreads();   // drains vmcnt: buf^1 staged; all reads of cur done
    cur ^= 1;
  }
#undef GSTAGE

#pragma unroll
  for (int nf = 0; nf < 2; ++nf) {
    const int col = n0 + wn*32 + nf*16 + l15;
    const float bv = bias[col];
#pragma unroll
    for (int mf = 0; mf < 4; ++mf) {
      const int rowb = m0 + wm*64 + mf*16 + l4*4;
#pragma unroll
      for (int r = 0; r < 4; ++r) {
        float v = (acc[mf][nf][r] + bv) * scale;
        if (OUT_BF16)
          ((unsigned short*)Cout)[(size_t)(rowb + r)*N + col] = f2bf(v);
        else
          ((float*)Cout)[(size_t)(rowb + r)*N + col] = v;
      }
    }
  }
}

// Fused Q/K/V projections: blockIdx.z selects which GEMM. 1536 blocks (3/CU).
__global__ __launch_bounds__(256, 2)
void gemm_qkv(const unsigned short* __restrict__ X0, const unsigned short* __restrict__ X1,
              const unsigned short* __restrict__ X2,
              const unsigned short* __restrict__ W0, const unsigned short* __restrict__ W1,
              const unsigned short* __restrict__ W2,
              const float* __restrict__ b0, const float* __restrict__ b1,
              const float* __restrict__ b2,
              unsigned short* __restrict__ C0, unsigned short* __restrict__ C1,
              unsigned short* __restrict__ C2, float scale0) {
  const int z = blockIdx.z;
  const unsigned short* A  = (z == 0) ? X0 : (z == 1) ? X1 : X2;
  const unsigned short* Bm = (z == 0) ? W0 : (z == 1) ? W1 : W2;
  const float* bias        = (z == 0) ? b0 : (z == 1) ? b1 : b2;
  unsigned short* C        = (z == 0) ? C0 : (z == 1) ? C1 : C2;
  const float scale        = (z == 0) ? scale0 : 1.0f;
  gemm_body<1>(A, Bm, bias, C, scale, blockIdx.x, blockIdx.y);
}

// Output projection (f32 out to d_out)
__global__ __launch_bounds__(256, 2)
void gemm_o(const unsigned short* __restrict__ A, const unsigned short* __restrict__ Bm,
            const float* __restrict__ bias, float* __restrict__ C) {
  gemm_body<0>(A, Bm, bias, C, 1.0f, blockIdx.x, blockIdx.y);
}

// ---------------------------------------------------------------------------
// Flash attention v5: q-split for occupancy. 1024 blocks = 32 qt x 32 bh,
// 4 waves x 16 q-rows = 64-q tile, full KV range (no combine pass).
// Per-wave compute byte-identical to R5/R7/R8/R10-verified attn_fwd3;
// 4-wave staging maps are R9-verified (attn_fwd4 passed correctness).
// LDS 40KB -> 4 blocks/CU co-resident (4 independent barrier groups).
// ---------------------------------------------------------------------------
__global__ __launch_bounds__(256, 4)
void attn_fwd5(const unsigned short* __restrict__ Q,
               const unsigned short* __restrict__ Kg,
               const unsigned short* __restrict__ Vg,
               unsigned short* __restrict__ O) {
  __shared__ __attribute__((aligned(16))) unsigned short Kl[2][4096];   // 8KB x2
  __shared__ __attribute__((aligned(16))) unsigned short Vt[2][4096];   // 8KB x2
  __shared__ __attribute__((aligned(16))) unsigned short Pl[4][1024];   // 2KB/wave

  const int tid = threadIdx.x;
  const int l = tid & 63, w = tid >> 6;        // w = 0..3
  const int l15 = l & 15, l4 = l >> 4, l7 = l & 7;

  // XCD-aware bijective decode: 1024 blocks; bits [2:0]=XCD, [4:3]=bh-sub, [9:5]=qt
  const int id = blockIdx.x;
  const int bh = (id & 7) * 4 + ((id >> 3) & 3);
  const int qt = id >> 5;                       // 0..31
  const int b = bh >> 4, h = bh & 15;
  const size_t bS = (size_t)b * SEQ;
  const int qw = qt * 64 + w * 16;              // wave's q base

  // Q fragments (held in regs): lane holds Q[q=qw+l15][e = ks*32 + l4*8 + j]
  short8 qf[2];
  {
    const char* qp = (const char*)Q + ((bS + qw + l15) * E_DIM + h * 64) * 2;
    qf[0] = *(const short8*)(qp + l4 * 16);
    qf[1] = *(const short8*)(qp + 64 + l4 * 16);
  }

  f32x4 zero = {0.f, 0.f, 0.f, 0.f};
  f32x4 oacc[4];                                 // O^T: d=df*16+l4*4+r, q=l15
#pragma unroll
  for (int i = 0; i < 4; ++i) oacc[i] = zero;
  float mrow = -1e30f, lrow = 0.f;

  // staging maps (4-wave forms, R9-verified)
  const int krow = l >> 3;                       // 0..7
  const int kcg  = (l & 7) ^ krow;               // inverse-swizzled source octet
  const int vrow = tid >> 3;                     // 0..31
  const int vdch = tid & 7;
  const int vd0  = vdch * 8;

#define KSTAGE(KT, BUF)                                                        \
  do {                                                                         \
    _Pragma("unroll")                                                          \
    for (int t = 0; t < 2; ++t) {                                              \
      int ia = w*2 + t;                                                        \
      gload_lds16((const char*)Kg +                                            \
          ((bS + (size_t)(KT)*64 + ia*8 + krow) * E_DIM + h*64 + kcg*8)*2,     \
          (char*)Kl[BUF] + ia * 1024);                                         \
    }                                                                          \
  } while (0)

#define VLOAD(KT, REP)                                                         \
  (*(const short8*)((const char*)Vg +                                          \
      ((bS + (size_t)(KT)*64 + (REP)*32 + vrow) * E_DIM + h*64 + vd0) * 2))

  // scatter Vt[buf][d][kv]: byte = d*128 + ((kvh ^ (d&7))<<4) + (kvl<<1)
#define VSCATTER(VV, BUF, REP)                                                 \
  do {                                                                         \
    const int row_ = (REP)*32 + vrow;                                          \
    char* vbase_ = (char*)Vt[BUF] + ((row_ & 7) << 1);                         \
    const int kvh_ = row_ >> 3;                                                \
    _Pragma("unroll")                                                          \
    for (int ei = 0; ei < 8; ++ei) {                                           \
      int e_ = (ei + vdch) & 7;                                                \
      int d_ = vd0 + e_;                                                       \
      *(unsigned short*)(vbase_ + d_ * 128 + ((kvh_ ^ e_) << 4)) =             \
          (unsigned short)(VV)[e_];                                            \
    }                                                                          \
  } while (0)

  // prologue: tile 0
  {
    short8 va = VLOAD(0, 0), vb2 = VLOAD(0, 1);
    KSTAGE(0, 0);
    VSCATTER(va, 0, 0);
    VSCATTER(vb2, 0, 1);
  }
  __syncthreads();

  int cur = 0;
  constexpr int NT = SEQ / 64;
  for (int kt = 0; kt < NT; ++kt) {
    short8 va, vb2;
    const bool more = (kt + 1 < NT);
    if (more) {
      KSTAGE(kt + 1, cur ^ 1);
      va  = VLOAD(kt + 1, 0);
      vb2 = VLOAD(kt + 1, 1);
    }

    // ---- S^T = K Q^T : lane -> S[kv = nf*16 + l4*4 + r][q = qw + l15] ----
    f32x4 s[4];
    const char* kb = (const char*)Kl[cur];
#pragma unroll
    for (int nf = 0; nf < 4; ++nf) {
      const char* rowb = kb + (nf * 16 + l15) * 128;
      short8 k0 = *(const short8*)(rowb + ((l4 ^ l7) << 4));
      short8 k1 = *(const short8*)(rowb + (((4 + l4) ^ l7) << 4));
      f32x4 z = zero;
      z = __builtin_amdgcn_mfma_f32_16x16x32_bf16(k0, qf[0], z, 0, 0, 0);
      z = __builtin_amdgcn_mfma_f32_16x16x32_bf16(k1, qf[1], z, 0, 0, 0);
      s[nf] = z;
    }

    // ---- online softmax: per-lane scalar (q = l15; l4-groups hold kv quarters)
    float mx = s[0][0];
#pragma unroll
    for (int nf = 0; nf < 4; ++nf)
#pragma unroll
      for (int r = 0; r < 4; ++r) mx = fmaxf(mx, s[nf][r]);
    mx = fmaxf(mx, __shfl_xor(mx, 16));
    mx = fmaxf(mx, __shfl_xor(mx, 32));
    const float mnew = fmaxf(mrow, mx);
    const float fac = __builtin_amdgcn_exp2f(mrow - mnew);
    mrow = mnew;

    float pv[4][4];
    float rs = 0.f;
#pragma unroll
    for (int nf = 0; nf < 4; ++nf)
#pragma unroll
      for (int r = 0; r < 4; ++r) {
        float p = __builtin_amdgcn_exp2f(s[nf][r] - mnew);
        pv[nf][r] = p;
        rs += p;
      }
    rs += __shfl_xor(rs, 16);
    rs += __shfl_xor(rs, 32);
    lrow = lrow * fac + rs;

    // ---- P -> per-wave LDS, packed b64, chunk-XOR swizzle by q(&7)=l7 ----
    unsigned short* pw = Pl[w];
#pragma unroll
    for (int nf = 0; nf < 4; ++nf) {
      const int c = nf * 2 + (l4 >> 1);
      i32x2 pk;
      pk.x = cvtpk(pv[nf][0], pv[nf][1]);
      pk.y = cvtpk(pv[nf][2], pv[nf][3]);
      *(i32x2*)((char*)pw + l15 * 128 + ((c ^ l7) << 4) + ((l4 & 1) << 3)) = pk;
    }
    // B-fragments: P[q=l15][kv = ks*32 + l4*8 + j]
    short8 pf0 = *(const short8*)((const char*)pw + l15 * 128 + ((l4 ^ l7) << 4));
    short8 pf1 = *(const short8*)((const char*)pw + l15 * 128 + (((4 + l4) ^ l7) << 4));

    // ---- rescale + O^T += V^T P^T ----
#pragma unroll
    for (int df = 0; df < 4; ++df)
#pragma unroll
      for (int r = 0; r < 4; ++r) oacc[df][r] *= fac;

    const char* vb = (const char*)Vt[cur];
#pragma unroll
    for (int df = 0; df < 4; ++df) {
      const char* rowb = vb + (df * 16 + l15) * 128;
      short8 v0 = *(const short8*)(rowb + ((l4 ^ l7) << 4));
      short8 v1 = *(const short8*)(rowb + (((4 + l4) ^ l7) << 4));
      oacc[df] = __builtin_amdgcn_mfma_f32_16x16x32_bf16(v0, pf0, oacc[df], 0, 0, 0);
      oacc[df] = __builtin_amdgcn_mfma_f32_16x16x32_bf16(v1, pf1, oacc[df], 0, 0, 0);
    }

    if (more) {
      VSCATTER(va, cur ^ 1, 0);
      VSCATTER(vb2, cur ^ 1, 1);
    }
    __syncthreads();   // drains vmcnt+lgkmcnt: next buffers staged, cur free
    cur ^= 1;
  }
#undef KSTAGE
#undef VLOAD
#undef VSCATTER

  // ---- epilogue: O[q = qw+l15][d = df*16 + l4*4 + r] ----
  const float rinv = __builtin_amdgcn_rcpf(lrow);
  unsigned short* orow = O + (bS + qw + l15) * E_DIM + h * 64;
#pragma unroll
  for (int df = 0; df < 4; ++df) {
    short4_t o4;
#pragma unroll
    for (int r = 0; r < 4; ++r) o4[r] = (short)f2bf(oacc[df][r] * rinv);
    *(short4_t*)(orow + df * 16 + l4 * 4) = o4;
  }
}

extern "C" void kernel_launch(void* const* d_in, const int* in_sizes, int n_in,
                              void* d_out, int out_size, void* d_ws, size_t ws_size,
                              hipStream_t stream) {
  const float* q_in = (const float*)d_in[0];
  const float* k_in = (const float*)d_in[1];
  const float* v_in = (const float*)d_in[2];
  const float* Wq = (const float*)d_in[3];
  const float* bq = (const float*)d_in[4];
  const float* Wk = (const float*)d_in[5];
  const float* bk = (const float*)d_in[6];
  const float* Wv = (const float*)d_in[7];
  const float* bv = (const float*)d_in[8];
  const float* Wo = (const float*)d_in[9];
  const float* bo = (const float*)d_in[10];

  char* ws = (char*)d_ws;
  const size_t XB = (size_t)M_ROWS * E_DIM * 2;   // 8 MiB
  const size_t WB = (size_t)E_DIM * E_DIM * 2;    // 2 MiB
  unsigned short* Xq  = (unsigned short*)(ws);
  unsigned short* Xk  = (unsigned short*)(ws + XB);
  unsigned short* Xv  = (unsigned short*)(ws + 2*XB);
  unsigned short* Wqb = (unsigned short*)(ws + 3*XB);
  unsigned short* Wkb = (unsigned short*)(ws + 3*XB + WB);
  unsigned short* Wvb = (unsigned short*)(ws + 3*XB + 2*WB);
  unsigned short* Wob = (unsigned short*)(ws + 3*XB + 3*WB);
  unsigned short* Qb  = (unsigned short*)(ws + 3*XB + 4*WB);
  unsigned short* Kb  = (unsigned short*)(ws + 4*XB + 4*WB);
  unsigned short* Vb  = (unsigned short*)(ws + 5*XB + 4*WB);
  unsigned short* Ob  = (unsigned short*)(ws + 6*XB + 4*WB);  // ends at 64 MiB

  const int nX8 = M_ROWS * E_DIM / 8;   // 524288
  const int nW8 = E_DIM * E_DIM / 8;    // 131072
  cvt3_f32_bf16<<<dim3(nX8/256, 3), 256, 0, stream>>>(q_in, k_in, v_in, Xq, Xk, Xv, nX8);
  cvt4_f32_bf16<<<dim3(nW8/256, 4), 256, 0, stream>>>(Wq, Wk, Wv, Wo, Wqb, Wkb, Wvb, Wob, nW8);

  const float qscale = 0.125f * 1.44269504088896340736f;  // scale * log2(e)
  dim3 qkvgrid(E_DIM/64, M_ROWS/128, 3);   // 16 x 32 x 3 = 1536 blocks
  gemm_qkv<<<qkvgrid, 256, 0, stream>>>(Xq, Xk, Xv, Wqb, Wkb, Wvb, bq, bk, bv,
                                        Qb, Kb, Vb, qscale);

  attn_fwd5<<<1024, 256, 0, stream>>>(Qb, Kb, Vb, Ob);   // 32 qt x 32 bh, xcd-swizzled

  dim3 ogrid(E_DIM/64, M_ROWS/128);        // 512 blocks
  gemm_o<<<ogrid, 256, 0, stream>>>(Ob, Wob, bo, (float*)d_out);
}

// Round 13
// 154.559 us; speedup vs baseline: 1.1320x; 1.1320x over previous
//
#include <hip/hip_runtime.h>
#include <stdint.h>

#define E_DIM 1024
#define N_HEADS 16
#define HEAD_D 64
#define BATCH 2
#define SEQ 2048
#define M_ROWS (BATCH*SEQ)   // 4096

typedef __attribute__((ext_vector_type(8))) short short8;
typedef __attribute__((ext_vector_type(4))) short short4_t;
typedef __attribute__((ext_vector_type(4))) float f32x4;
typedef __attribute__((ext_vector_type(4))) int i32x4;
typedef __attribute__((ext_vector_type(2))) int i32x2;

__device__ __forceinline__ unsigned short f2bf(float f) {
  uint32_t u = __float_as_uint(f);
  u += 0x7FFFu + ((u >> 16) & 1u);   // RTNE
  return (unsigned short)(u >> 16);
}

// async global->LDS, 16B per lane; LDS dest = wave-uniform base + lane*16
__device__ __forceinline__ void gload_lds16(const void* g, void* l) {
  __builtin_amdgcn_global_load_lds(
      (const __attribute__((address_space(1))) uint32_t*)(uintptr_t)g,
      (__attribute__((address_space(3))) uint32_t*)(uint32_t)(uintptr_t)l,
      16, 0, 0);
}

__device__ __forceinline__ int cvtpk(float lo, float hi) {
  int r;
  asm("v_cvt_pk_bf16_f32 %0, %1, %2" : "=v"(r) : "v"(lo), "v"(hi));
  return r;
}

__device__ __forceinline__ void cvt_body(const float* __restrict__ src,
                                         unsigned short* __restrict__ dst, int i) {
  f32x4 a = ((const f32x4*)src)[2*i];
  f32x4 b = ((const f32x4*)src)[2*i + 1];
  union { unsigned short us[8]; i32x4 v; } o;
  o.us[0] = f2bf(a[0]); o.us[1] = f2bf(a[1]);
  o.us[2] = f2bf(a[2]); o.us[3] = f2bf(a[3]);
  o.us[4] = f2bf(b[0]); o.us[5] = f2bf(b[1]);
  o.us[6] = f2bf(b[2]); o.us[7] = f2bf(b[3]);
  ((i32x4*)dst)[i] = o.v;
}

// 3 equal-size f32->bf16 converts in one launch (blockIdx.y selects)
__global__ void cvt3_f32_bf16(const float* __restrict__ s0, const float* __restrict__ s1,
                              const float* __restrict__ s2,
                              unsigned short* __restrict__ d0, unsigned short* __restrict__ d1,
                              unsigned short* __restrict__ d2, int n8) {
  int i = blockIdx.x * blockDim.x + threadIdx.x;
  if (i >= n8) return;
  const float* s = (blockIdx.y == 0) ? s0 : (blockIdx.y == 1) ? s1 : s2;
  unsigned short* d = (blockIdx.y == 0) ? d0 : (blockIdx.y == 1) ? d1 : d2;
  cvt_body(s, d, i);
}

// 4 equal-size f32->bf16 converts in one launch
__global__ void cvt4_f32_bf16(const float* __restrict__ s0, const float* __restrict__ s1,
                              const float* __restrict__ s2, const float* __restrict__ s3,
                              unsigned short* __restrict__ d0, unsigned short* __restrict__ d1,
                              unsigned short* __restrict__ d2, unsigned short* __restrict__ d3,
                              int n8) {
  int i = blockIdx.x * blockDim.x + threadIdx.x;
  if (i >= n8) return;
  const float* s = (blockIdx.y == 0) ? s0 : (blockIdx.y == 1) ? s1
                 : (blockIdx.y == 2) ? s2 : s3;
  unsigned short* d = (blockIdx.y == 0) ? d0 : (blockIdx.y == 1) ? d1
                    : (blockIdx.y == 2) ? d2 : d3;
  cvt_body(s, d, i);
}

// ---------------------------------------------------------------------------
// GEMM body (R8/R9/R10-verified loop): C = (A B^T + bias) * scale.
// OUT_MODE: 0 = f32 normal; 1 = bf16 normal; 2 = bf16 TRANSPOSED per head:
//   Vt[((b*16+h)*64 + d)*SEQ + s], b=row>>11, s=row&2047, h=col>>6, d=col&63.
// ---------------------------------------------------------------------------
template<int OUT_MODE>
__device__ __forceinline__ void gemm_body(const unsigned short* __restrict__ A,
                                          const unsigned short* __restrict__ Bm,
                                          const float* __restrict__ bias,
                                          void* __restrict__ Cout,
                                          float scale, int bx, int by) {
  constexpr int BM = 128, BN = 64, BK = 64, K = E_DIM, N = E_DIM;
  __shared__ __attribute__((aligned(16))) unsigned short Al[2][BM*BK];  // 16KB x2
  __shared__ __attribute__((aligned(16))) unsigned short Bl[2][BN*BK];  //  8KB x2
  const int tid  = threadIdx.x;
  const int lane = tid & 63, w = tid >> 6;
  const int wm = w >> 1, wn = w & 1;          // wave tile 64x32
  const int l15 = lane & 15, l4 = lane >> 4, l7 = lane & 7;
  const int m0 = by * BM, n0 = bx * BN;
  const int jr = lane >> 3, jc = lane & 7;
  const int kcg = jc ^ jr;                    // inverse-swizzled source chunk

#define GSTAGE(KT, BUF)                                                        \
  do {                                                                         \
    _Pragma("unroll")                                                          \
    for (int t = 0; t < 4; ++t) {            /* A: 16 issues of 1KB, 4/wave */ \
      int ia = w*4 + t;                                                        \
      const char* src = (const char*)A +                                       \
          ((size_t)(m0 + ia*8 + jr)*K + (KT))*2 + (kcg << 4);                  \
      gload_lds16(src, (char*)Al[BUF] + ia*1024);                              \
    }                                                                          \
    _Pragma("unroll")                                                          \
    for (int t = 0; t < 2; ++t) {            /* B: 8 issues, 2/wave */         \
      int ib = w*2 + t;                                                        \
      const char* src = (const char*)Bm +                                      \
          ((size_t)(n0 + ib*8 + jr)*K + (KT))*2 + (kcg << 4);                  \
      gload_lds16(src, (char*)Bl[BUF] + ib*1024);                              \
    }                                                                          \
  } while (0)

  f32x4 zero = {0.f, 0.f, 0.f, 0.f};
  f32x4 acc[4][2];
  for (int i = 0; i < 4; ++i) for (int j = 0; j < 2; ++j) acc[i][j] = zero;

  GSTAGE(0, 0);
  __syncthreads();

  int cur = 0;
  const int NKT = K / BK;
  for (int kt = 0; kt < NKT; ++kt) {
    if (kt + 1 < NKT) GSTAGE((kt + 1) * BK, cur ^ 1);

#pragma unroll
    for (int ks = 0; ks < 2; ++ks) {
      const int sw = ((ks*4 + l4) ^ l7) << 4;
      short8 af[4], bf[2];
#pragma unroll
      for (int mf = 0; mf < 4; ++mf)
        af[mf] = *(const short8*)((const char*)Al[cur] + (wm*64 + mf*16 + l15)*128 + sw);
#pragma unroll
      for (int nf = 0; nf < 2; ++nf)
        bf[nf] = *(const short8*)((const char*)Bl[cur] + (wn*32 + nf*16 + l15)*128 + sw);
#pragma unroll
      for (int mf = 0; mf < 4; ++mf)
#pragma unroll
        for (int nf = 0; nf < 2; ++nf)
          acc[mf][nf] = __builtin_amdgcn_mfma_f32_16x16x32_bf16(
              af[mf], bf[nf], acc[mf][nf], 0, 0, 0);
    }

    __syncthreads();   // drains vmcnt: buf^1 staged; all reads of cur done
    cur ^= 1;
  }
#undef GSTAGE

#pragma unroll
  for (int nf = 0; nf < 2; ++nf) {
    const int col = n0 + wn*32 + nf*16 + l15;
    const float bv = bias[col];
#pragma unroll
    for (int mf = 0; mf < 4; ++mf) {
      const int rowb = m0 + wm*64 + mf*16 + l4*4;
      if (OUT_MODE == 2) {
        short4_t o4;
#pragma unroll
        for (int r = 0; r < 4; ++r) o4[r] = (short)f2bf(acc[mf][nf][r] + bv);
        const size_t addr =
            ((size_t)((rowb >> 11) * 16 + (col >> 6)) * 64 + (col & 63)) * SEQ
            + (rowb & 2047);
        *(short4_t*)((unsigned short*)Cout + addr) = o4;
      } else {
#pragma unroll
        for (int r = 0; r < 4; ++r) {
          float v = (acc[mf][nf][r] + bv) * scale;
          if (OUT_MODE == 1)
            ((unsigned short*)Cout)[(size_t)(rowb + r)*N + col] = f2bf(v);
          else
            ((float*)Cout)[(size_t)(rowb + r)*N + col] = v;
        }
      }
    }
  }
}

// Fused Q/K/V projections: blockIdx.z selects. z==2 writes V TRANSPOSED (Vt).
__global__ __launch_bounds__(256, 2)
void gemm_qkv(const unsigned short* __restrict__ X0, const unsigned short* __restrict__ X1,
              const unsigned short* __restrict__ X2,
              const unsigned short* __restrict__ W0, const unsigned short* __restrict__ W1,
              const unsigned short* __restrict__ W2,
              const float* __restrict__ b0, const float* __restrict__ b1,
              const float* __restrict__ b2,
              unsigned short* __restrict__ C0, unsigned short* __restrict__ C1,
              unsigned short* __restrict__ Vt, float scale0) {
  const int z = blockIdx.z;
  if (z == 2) {
    gemm_body<2>(X2, W2, b2, Vt, 1.0f, blockIdx.x, blockIdx.y);
  } else {
    const unsigned short* A  = (z == 0) ? X0 : X1;
    const unsigned short* Bm = (z == 0) ? W0 : W1;
    const float* bias        = (z == 0) ? b0 : b1;
    unsigned short* C        = (z == 0) ? C0 : C1;
    const float scale        = (z == 0) ? scale0 : 1.0f;
    gemm_body<1>(A, Bm, bias, C, scale, blockIdx.x, blockIdx.y);
  }
}

// Output projection (f32 out to d_out)
__global__ __launch_bounds__(256, 2)
void gemm_o(const unsigned short* __restrict__ A, const unsigned short* __restrict__ Bm,
            const float* __restrict__ bias, float* __restrict__ C) {
  gemm_body<0>(A, Bm, bias, C, 1.0f, blockIdx.x, blockIdx.y);
}

// ---------------------------------------------------------------------------
// Flash attention v6: EXACT R10 schedule (8 waves x 16 q, 512 blocks), but V
// arrives pre-transposed (Vt global, [.. d][s]) so V staging is the verified
// K-staging pattern (1 gload_lds16/wave) — VLOAD/VSCATTER deleted.
// LDS chunk algebra: staged chunk c holds kv-octet c^(d&7); fragment read at
// (ks*4+l4)^(d&7) yields kv = ks*32+l4*8+j — identical to R10's layout.
// ---------------------------------------------------------------------------
__global__ __launch_bounds__(512, 2)
void attn_fwd6(const unsigned short* __restrict__ Q,
               const unsigned short* __restrict__ Kg,
               const unsigned short* __restrict__ Vt_g,
               unsigned short* __restrict__ O) {
  __shared__ __attribute__((aligned(16))) unsigned short Kl[2][4096];
  __shared__ __attribute__((aligned(16))) unsigned short Vl[2][4096];
  __shared__ __attribute__((aligned(16))) unsigned short Pl[8][1024];

  const int tid = threadIdx.x;
  const int l = tid & 63, w = tid >> 6;
  const int l15 = l & 15, l4 = l >> 4, l7 = l & 7;

  // XCD-aware bijective decode: 512 blocks = 16 qt x 32 bh; XCD x gets bh 4x..4x+3
  const int id = blockIdx.x;
  const int bh = (id & 7) * 4 + ((id >> 3) & 3);
  const int qt = id >> 5;
  const int b = bh >> 4, h = bh & 15;
  const size_t bS = (size_t)b * SEQ;
  const int qw = qt * 128 + w * 16;             // wave's q base

  // Q fragments (held in regs): lane holds Q[q=qw+l15][e = ks*32 + l4*8 + j]
  short8 qf[2];
  {
    const char* qp = (const char*)Q + ((bS + qw + l15) * E_DIM + h * 64) * 2;
    qf[0] = *(const short8*)(qp + l4 * 16);
    qf[1] = *(const short8*)(qp + 64 + l4 * 16);
  }

  f32x4 zero = {0.f, 0.f, 0.f, 0.f};
  f32x4 oacc[4];                                 // O^T: d=df*16+l4*4+r, q=l15
#pragma unroll
  for (int i = 0; i < 4; ++i) oacc[i] = zero;
  float mrow = -1e30f, lrow = 0.f;

  // staging maps
  const int krow = l >> 3;                       // 0..7
  const int kcg  = (l & 7) ^ krow;               // inverse-swizzled source octet
  const char* vt_base = (const char*)Vt_g +
      ((size_t)((b * 16 + h) * 64 + 8 * w + krow) * SEQ) * 2 + (kcg << 4);

#define KSTAGE(KT, BUF)                                                        \
  gload_lds16((const char*)Kg +                                                \
                  ((bS + (size_t)(KT)*64 + 8*w + krow) * E_DIM + h*64 + kcg*8)*2, \
              (char*)Kl[BUF] + w * 1024)

#define VSTAGE(KT, BUF)                                                        \
  gload_lds16(vt_base + (size_t)(KT) * 128, (char*)Vl[BUF] + w * 1024)

  // prologue: tile 0
  KSTAGE(0, 0);
  VSTAGE(0, 0);
  __syncthreads();

  int cur = 0;
  constexpr int NT = SEQ / 64;
  for (int kt = 0; kt < NT; ++kt) {
    const bool more = (kt + 1 < NT);
    if (more) {
      KSTAGE(kt + 1, cur ^ 1);
      VSTAGE(kt + 1, cur ^ 1);
    }

    // ---- S^T = K Q^T : lane -> S[kv = nf*16 + l4*4 + r][q = qw + l15] ----
    f32x4 s[4];
    const char* kb = (const char*)Kl[cur];
#pragma unroll
    for (int nf = 0; nf < 4; ++nf) {
      const char* rowb = kb + (nf * 16 + l15) * 128;
      short8 k0 = *(const short8*)(rowb + ((l4 ^ l7) << 4));
      short8 k1 = *(const short8*)(rowb + (((4 + l4) ^ l7) << 4));
      f32x4 z = zero;
      z = __builtin_amdgcn_mfma_f32_16x16x32_bf16(k0, qf[0], z, 0, 0, 0);
      z = __builtin_amdgcn_mfma_f32_16x16x32_bf16(k1, qf[1], z, 0, 0, 0);
      s[nf] = z;
    }

    // ---- online softmax: per-lane scalar (q = l15; l4-groups hold kv quarters)
    float mx = s[0][0];
#pragma unroll
    for (int nf = 0; nf < 4; ++nf)
#pragma unroll
      for (int r = 0; r < 4; ++r) mx = fmaxf(mx, s[nf][r]);
    mx = fmaxf(mx, __shfl_xor(mx, 16));
    mx = fmaxf(mx, __shfl_xor(mx, 32));
    const float mnew = fmaxf(mrow, mx);
    const float fac = __builtin_amdgcn_exp2f(mrow - mnew);
    mrow = mnew;

    float pv[4][4];
    float rs = 0.f;
#pragma unroll
    for (int nf = 0; nf < 4; ++nf)
#pragma unroll
      for (int r = 0; r < 4; ++r) {
        float p = __builtin_amdgcn_exp2f(s[nf][r] - mnew);
        pv[nf][r] = p;
        rs += p;
      }
    rs += __shfl_xor(rs, 16);
    rs += __shfl_xor(rs, 32);
    lrow = lrow * fac + rs;

    // ---- P -> per-wave LDS, packed b64, chunk-XOR swizzle by q(&7)=l7 ----
    unsigned short* pw = Pl[w];
#pragma unroll
    for (int nf = 0; nf < 4; ++nf) {
      const int c = nf * 2 + (l4 >> 1);
      i32x2 pk;
      pk.x = cvtpk(pv[nf][0], pv[nf][1]);
      pk.y = cvtpk(pv[nf][2], pv[nf][3]);
      *(i32x2*)((char*)pw + l15 * 128 + ((c ^ l7) << 4) + ((l4 & 1) << 3)) = pk;
    }
    // B-fragments: P[q=l15][kv = ks*32 + l4*8 + j]
    short8 pf0 = *(const short8*)((const char*)pw + l15 * 128 + ((l4 ^ l7) << 4));
    short8 pf1 = *(const short8*)((const char*)pw + l15 * 128 + (((4 + l4) ^ l7) << 4));

    // ---- rescale + O^T += V^T P^T ----
#pragma unroll
    for (int df = 0; df < 4; ++df)
#pragma unroll
      for (int r = 0; r < 4; ++r) oacc[df][r] *= fac;

    const char* vb = (const char*)Vl[cur];
#pragma unroll
    for (int df = 0; df < 4; ++df) {
      const char* rowb = vb + (df * 16 + l15) * 128;
      short8 v0 = *(const short8*)(rowb + ((l4 ^ l7) << 4));
      short8 v1 = *(const short8*)(rowb + (((4 + l4) ^ l7) << 4));
      oacc[df] = __builtin_amdgcn_mfma_f32_16x16x32_bf16(v0, pf0, oacc[df], 0, 0, 0);
      oacc[df] = __builtin_amdgcn_mfma_f32_16x16x32_bf16(v1, pf1, oacc[df], 0, 0, 0);
    }

    __syncthreads();   // drains vmcnt+lgkmcnt: next buffers staged, cur free
    cur ^= 1;
  }
#undef KSTAGE
#undef VSTAGE

  // ---- epilogue: O[q = qw+l15][d = df*16 + l4*4 + r] ----
  const float rinv = __builtin_amdgcn_rcpf(lrow);
  unsigned short* orow = O + (bS + qw + l15) * E_DIM + h * 64;
#pragma unroll
  for (int df = 0; df < 4; ++df) {
    short4_t o4;
#pragma unroll
    for (int r = 0; r < 4; ++r) o4[r] = (short)f2bf(oacc[df][r] * rinv);
    *(short4_t*)(orow + df * 16 + l4 * 4) = o4;
  }
}

extern "C" void kernel_launch(void* const* d_in, const int* in_sizes, int n_in,
                              void* d_out, int out_size, void* d_ws, size_t ws_size,
                              hipStream_t stream) {
  const float* q_in = (const float*)d_in[0];
  const float* k_in = (const float*)d_in[1];
  const float* v_in = (const float*)d_in[2];
  const float* Wq = (const float*)d_in[3];
  const float* bq = (const float*)d_in[4];
  const float* Wk = (const float*)d_in[5];
  const float* bk = (const float*)d_in[6];
  const float* Wv = (const float*)d_in[7];
  const float* bv = (const float*)d_in[8];
  const float* Wo = (const float*)d_in[9];
  const float* bo = (const float*)d_in[10];

  char* ws = (char*)d_ws;
  const size_t XB = (size_t)M_ROWS * E_DIM * 2;   // 8 MiB
  const size_t WB = (size_t)E_DIM * E_DIM * 2;    // 2 MiB
  unsigned short* Xq  = (unsigned short*)(ws);
  unsigned short* Xk  = (unsigned short*)(ws + XB);
  unsigned short* Xv  = (unsigned short*)(ws + 2*XB);
  unsigned short* Wqb = (unsigned short*)(ws + 3*XB);
  unsigned short* Wkb = (unsigned short*)(ws + 3*XB + WB);
  unsigned short* Wvb = (unsigned short*)(ws + 3*XB + 2*WB);
  unsigned short* Wob = (unsigned short*)(ws + 3*XB + 3*WB);
  unsigned short* Qb  = (unsigned short*)(ws + 3*XB + 4*WB);
  unsigned short* Kb  = (unsigned short*)(ws + 4*XB + 4*WB);
  unsigned short* Vtg = (unsigned short*)(ws + 5*XB + 4*WB);  // V^T per head
  unsigned short* Ob  = (unsigned short*)(ws + 6*XB + 4*WB);  // ends at 64 MiB

  const int nX8 = M_ROWS * E_DIM / 8;   // 524288
  const int nW8 = E_DIM * E_DIM / 8;    // 131072
  cvt3_f32_bf16<<<dim3(nX8/256, 3), 256, 0, stream>>>(q_in, k_in, v_in, Xq, Xk, Xv, nX8);
  cvt4_f32_bf16<<<dim3(nW8/256, 4), 256, 0, stream>>>(Wq, Wk, Wv, Wo, Wqb, Wkb, Wvb, Wob, nW8);

  const float qscale = 0.125f * 1.44269504088896340736f;  // scale * log2(e)
  dim3 qkvgrid(E_DIM/64, M_ROWS/128, 3);   // 16 x 32 x 3 = 1536 blocks
  gemm_qkv<<<qkvgrid, 256, 0, stream>>>(Xq, Xk, Xv, Wqb, Wkb, Wvb, bq, bk, bv,
                                        Qb, Kb, Vtg, qscale);

  attn_fwd6<<<512, 512, 0, stream>>>(Qb, Kb, Vtg, Ob);   // 16 qt x 32 bh, xcd-swizzled

  dim3 ogrid(E_DIM/64, M_ROWS/128);        // 512 blocks
  gemm_o<<<ogrid, 256, 0, stream>>>(Ob, Wob, bo, (float*)d_out);
}

// Round 14
// 123.422 us; speedup vs baseline: 1.4176x; 1.2523x over previous
//
#include <hip/hip_runtime.h>
#include <stdint.h>

#define E_DIM 1024
#define N_HEADS 16
#define HEAD_D 64
#define BATCH 2
#define SEQ 2048
#define M_ROWS (BATCH*SEQ)   // 4096

typedef __attribute__((ext_vector_type(8))) short short8;
typedef __attribute__((ext_vector_type(4))) short short4_t;
typedef __attribute__((ext_vector_type(4))) float f32x4;
typedef __attribute__((ext_vector_type(4))) int i32x4;
typedef __attribute__((ext_vector_type(2))) int i32x2;

__device__ __forceinline__ unsigned short f2bf(float f) {
  uint32_t u = __float_as_uint(f);
  u += 0x7FFFu + ((u >> 16) & 1u);   // RTNE
  return (unsigned short)(u >> 16);
}

// async global->LDS, 16B per lane; LDS dest = wave-uniform base + lane*16
__device__ __forceinline__ void gload_lds16(const void* g, void* l) {
  __builtin_amdgcn_global_load_lds(
      (const __attribute__((address_space(1))) uint32_t*)(uintptr_t)g,
      (__attribute__((address_space(3))) uint32_t*)(uint32_t)(uintptr_t)l,
      16, 0, 0);
}

__device__ __forceinline__ int cvtpk(float lo, float hi) {
  int r;
  asm("v_cvt_pk_bf16_f32 %0, %1, %2" : "=v"(r) : "v"(lo), "v"(hi));
  return r;
}

__device__ __forceinline__ void cvt_body(const float* __restrict__ src,
                                         unsigned short* __restrict__ dst, int i) {
  f32x4 a = ((const f32x4*)src)[2*i];
  f32x4 b = ((const f32x4*)src)[2*i + 1];
  union { unsigned short us[8]; i32x4 v; } o;
  o.us[0] = f2bf(a[0]); o.us[1] = f2bf(a[1]);
  o.us[2] = f2bf(a[2]); o.us[3] = f2bf(a[3]);
  o.us[4] = f2bf(b[0]); o.us[5] = f2bf(b[1]);
  o.us[6] = f2bf(b[2]); o.us[7] = f2bf(b[3]);
  ((i32x4*)dst)[i] = o.v;
}

// 3 equal-size f32->bf16 converts in one launch (blockIdx.y selects)
__global__ void cvt3_f32_bf16(const float* __restrict__ s0, const float* __restrict__ s1,
                              const float* __restrict__ s2,
                              unsigned short* __restrict__ d0, unsigned short* __restrict__ d1,
                              unsigned short* __restrict__ d2, int n8) {
  int i = blockIdx.x * blockDim.x + threadIdx.x;
  if (i >= n8) return;
  const float* s = (blockIdx.y == 0) ? s0 : (blockIdx.y == 1) ? s1 : s2;
  unsigned short* d = (blockIdx.y == 0) ? d0 : (blockIdx.y == 1) ? d1 : d2;
  cvt_body(s, d, i);
}

// 4 equal-size f32->bf16 converts in one launch
__global__ void cvt4_f32_bf16(const float* __restrict__ s0, const float* __restrict__ s1,
                              const float* __restrict__ s2, const float* __restrict__ s3,
                              unsigned short* __restrict__ d0, unsigned short* __restrict__ d1,
                              unsigned short* __restrict__ d2, unsigned short* __restrict__ d3,
                              int n8) {
  int i = blockIdx.x * blockDim.x + threadIdx.x;
  if (i >= n8) return;
  const float* s = (blockIdx.y == 0) ? s0 : (blockIdx.y == 1) ? s1
                 : (blockIdx.y == 2) ? s2 : s3;
  unsigned short* d = (blockIdx.y == 0) ? d0 : (blockIdx.y == 1) ? d1
                    : (blockIdx.y == 2) ? d2 : d3;
  cvt_body(s, d, i);
}

// ---------------------------------------------------------------------------
// GEMM body, runtime-parameterized epilogue (single instantiation per kernel):
// C[m][n] = (sum_k A[m][k]*Bm[n][k] + bias[brow ? m : n]) * scale, bf16 out.
// Main loop is the R8/R9/R10-verified 128x64 single-barrier double-buffer.
// Nstr = output row stride (runtime); K fixed at 1024.
// ---------------------------------------------------------------------------
__device__ __forceinline__ void gemm_body_rt(const unsigned short* __restrict__ A,
                                             const unsigned short* __restrict__ Bm,
                                             const float* __restrict__ bias,
                                             unsigned short* __restrict__ Cout,
                                             float scale, int bx, int by,
                                             int Nstr, bool brow) {
  constexpr int BM = 128, BN = 64, BK = 64, K = E_DIM;
  __shared__ __attribute__((aligned(16))) unsigned short Al[2][BM*BK];  // 16KB x2
  __shared__ __attribute__((aligned(16))) unsigned short Bl[2][BN*BK];  //  8KB x2
  const int tid  = threadIdx.x;
  const int lane = tid & 63, w = tid >> 6;
  const int wm = w >> 1, wn = w & 1;          // wave tile 64x32
  const int l15 = lane & 15, l4 = lane >> 4, l7 = lane & 7;
  const int m0 = by * BM, n0 = bx * BN;
  const int jr = lane >> 3, jc = lane & 7;
  const int kcg = jc ^ jr;                    // inverse-swizzled source chunk

#define GSTAGE(KT, BUF)                                                        \
  do {                                                                         \
    _Pragma("unroll")                                                          \
    for (int t = 0; t < 4; ++t) {            /* A: 16 issues of 1KB, 4/wave */ \
      int ia = w*4 + t;                                                        \
      const char* src = (const char*)A +                                       \
          ((size_t)(m0 + ia*8 + jr)*K + (KT))*2 + (kcg << 4);                  \
      gload_lds16(src, (char*)Al[BUF] + ia*1024);                              \
    }                                                                          \
    _Pragma("unroll")                                                          \
    for (int t = 0; t < 2; ++t) {            /* B: 8 issues, 2/wave */         \
      int ib = w*2 + t;                                                        \
      const char* src = (const char*)Bm +                                      \
          ((size_t)(n0 + ib*8 + jr)*K + (KT))*2 + (kcg << 4);                  \
      gload_lds16(src, (char*)Bl[BUF] + ib*1024);                              \
    }                                                                          \
  } while (0)

  f32x4 zero = {0.f, 0.f, 0.f, 0.f};
  f32x4 acc[4][2];
  for (int i = 0; i < 4; ++i) for (int j = 0; j < 2; ++j) acc[i][j] = zero;

  GSTAGE(0, 0);
  __syncthreads();

  int cur = 0;
  const int NKT = K / BK;
  for (int kt = 0; kt < NKT; ++kt) {
    if (kt + 1 < NKT) GSTAGE((kt + 1) * BK, cur ^ 1);

#pragma unroll
    for (int ks = 0; ks < 2; ++ks) {
      const int sw = ((ks*4 + l4) ^ l7) << 4;
      short8 af[4], bf[2];
#pragma unroll
      for (int mf = 0; mf < 4; ++mf)
        af[mf] = *(const short8*)((const char*)Al[cur] + (wm*64 + mf*16 + l15)*128 + sw);
#pragma unroll
      for (int nf = 0; nf < 2; ++nf)
        bf[nf] = *(const short8*)((const char*)Bl[cur] + (wn*32 + nf*16 + l15)*128 + sw);
#pragma unroll
      for (int mf = 0; mf < 4; ++mf)
#pragma unroll
        for (int nf = 0; nf < 2; ++nf)
          acc[mf][nf] = __builtin_amdgcn_mfma_f32_16x16x32_bf16(
              af[mf], bf[nf], acc[mf][nf], 0, 0, 0);
    }

    __syncthreads();   // drains vmcnt: buf^1 staged; all reads of cur done
    cur ^= 1;
  }
#undef GSTAGE

#pragma unroll
  for (int nf = 0; nf < 2; ++nf) {
    const int col = n0 + wn*32 + nf*16 + l15;
    const float bcol = brow ? 0.f : bias[col];
#pragma unroll
    for (int mf = 0; mf < 4; ++mf) {
      const int rowb = m0 + wm*64 + mf*16 + l4*4;
#pragma unroll
      for (int r = 0; r < 4; ++r) {
        const float bv = brow ? bias[rowb + r] : bcol;
        float v = (acc[mf][nf][r] + bv) * scale;
        Cout[(size_t)(rowb + r)*Nstr + col] = f2bf(v);
      }
    }
  }
}

// Fused Q/K/V projections. z==2 computes V^T = Wv * Xv^T (operand swap) ->
// Vt[(h*64+d)*M_ROWS + b*SEQ + s], coalesced stores. Grid (512, 1, 3).
__global__ __launch_bounds__(256, 2)
void gemm_qkv(const unsigned short* __restrict__ Xq, const unsigned short* __restrict__ Xk,
              const unsigned short* __restrict__ Xv,
              const unsigned short* __restrict__ Wq, const unsigned short* __restrict__ Wk,
              const unsigned short* __restrict__ Wv,
              const float* __restrict__ bq, const float* __restrict__ bk,
              const float* __restrict__ bv,
              unsigned short* __restrict__ Qb, unsigned short* __restrict__ Kb,
              unsigned short* __restrict__ Vt, float scale0) {
  const int z = blockIdx.z;
  const int idx = blockIdx.x;
  if (z == 2) {
    // A = Wv [1024][1024], Bm = Xv [4096][1024]; M=1024 (e), N=4096 (b*SEQ+s)
    gemm_body_rt(Wv, Xv, bv, Vt, 1.0f, idx & 63, idx >> 6, M_ROWS, true);
  } else {
    const unsigned short* A  = (z == 0) ? Xq : Xk;
    const unsigned short* Bm = (z == 0) ? Wq : Wk;
    const float* bias        = (z == 0) ? bq : bk;
    unsigned short* C        = (z == 0) ? Qb : Kb;
    const float scale        = (z == 0) ? scale0 : 1.0f;
    gemm_body_rt(A, Bm, bias, C, scale, idx & 15, idx >> 4, E_DIM, false);
  }
}

// Output projection, f32 out to d_out (separate kernel -> own 48KB LDS).
__global__ __launch_bounds__(256, 2)
void gemm_o(const unsigned short* __restrict__ A, const unsigned short* __restrict__ Bm,
            const float* __restrict__ bias, float* __restrict__ Cout) {
  constexpr int BM = 128, BN = 64, BK = 64, K = E_DIM, N = E_DIM;
  __shared__ __attribute__((aligned(16))) unsigned short Al[2][BM*BK];
  __shared__ __attribute__((aligned(16))) unsigned short Bl[2][BN*BK];
  const int tid  = threadIdx.x;
  const int lane = tid & 63, w = tid >> 6;
  const int wm = w >> 1, wn = w & 1;
  const int l15 = lane & 15, l4 = lane >> 4, l7 = lane & 7;
  const int m0 = blockIdx.y * BM, n0 = blockIdx.x * BN;
  const int jr = lane >> 3, jc = lane & 7;
  const int kcg = jc ^ jr;

#define GSTAGE(KT, BUF)                                                        \
  do {                                                                         \
    _Pragma("unroll")                                                          \
    for (int t = 0; t < 4; ++t) {                                              \
      int ia = w*4 + t;                                                        \
      const char* src = (const char*)A +                                       \
          ((size_t)(m0 + ia*8 + jr)*K + (KT))*2 + (kcg << 4);                  \
      gload_lds16(src, (char*)Al[BUF] + ia*1024);                              \
    }                                                                          \
    _Pragma("unroll")                                                          \
    for (int t = 0; t < 2; ++t) {                                              \
      int ib = w*2 + t;                                                        \
      const char* src = (const char*)Bm +                                      \
          ((size_t)(n0 + ib*8 + jr)*K + (KT))*2 + (kcg << 4);                  \
      gload_lds16(src, (char*)Bl[BUF] + ib*1024);                              \
    }                                                                          \
  } while (0)

  f32x4 zero = {0.f, 0.f, 0.f, 0.f};
  f32x4 acc[4][2];
  for (int i = 0; i < 4; ++i) for (int j = 0; j < 2; ++j) acc[i][j] = zero;

  GSTAGE(0, 0);
  __syncthreads();

  int cur = 0;
  const int NKT = K / BK;
  for (int kt = 0; kt < NKT; ++kt) {
    if (kt + 1 < NKT) GSTAGE((kt + 1) * BK, cur ^ 1);
#pragma unroll
    for (int ks = 0; ks < 2; ++ks) {
      const int sw = ((ks*4 + l4) ^ l7) << 4;
      short8 af[4], bf[2];
#pragma unroll
      for (int mf = 0; mf < 4; ++mf)
        af[mf] = *(const short8*)((const char*)Al[cur] + (wm*64 + mf*16 + l15)*128 + sw);
#pragma unroll
      for (int nf = 0; nf < 2; ++nf)
        bf[nf] = *(const short8*)((const char*)Bl[cur] + (wn*32 + nf*16 + l15)*128 + sw);
#pragma unroll
      for (int mf = 0; mf < 4; ++mf)
#pragma unroll
        for (int nf = 0; nf < 2; ++nf)
          acc[mf][nf] = __builtin_amdgcn_mfma_f32_16x16x32_bf16(
              af[mf], bf[nf], acc[mf][nf], 0, 0, 0);
    }
    __syncthreads();
    cur ^= 1;
  }
#undef GSTAGE

#pragma unroll
  for (int nf = 0; nf < 2; ++nf) {
    const int col = n0 + wn*32 + nf*16 + l15;
    const float bv = bias[col];
#pragma unroll
    for (int mf = 0; mf < 4; ++mf) {
      const int rowb = m0 + wm*64 + mf*16 + l4*4;
#pragma unroll
      for (int r = 0; r < 4; ++r)
        Cout[(size_t)(rowb + r)*N + col] = acc[mf][nf][r] + bv;
    }
  }
}

// ---------------------------------------------------------------------------
// Flash attention v6 (R13-verified): 8 waves x 16 q, 512 blocks; V arrives
// pre-transposed. Only change vs R13: Vt layout is (h*64+d)*M_ROWS + b*SEQ + s.
// ---------------------------------------------------------------------------
__global__ __launch_bounds__(512, 2)
void attn_fwd6(const unsigned short* __restrict__ Q,
               const unsigned short* __restrict__ Kg,
               const unsigned short* __restrict__ Vt_g,
               unsigned short* __restrict__ O) {
  __shared__ __attribute__((aligned(16))) unsigned short Kl[2][4096];
  __shared__ __attribute__((aligned(16))) unsigned short Vl[2][4096];
  __shared__ __attribute__((aligned(16))) unsigned short Pl[8][1024];

  const int tid = threadIdx.x;
  const int l = tid & 63, w = tid >> 6;
  const int l15 = l & 15, l4 = l >> 4, l7 = l & 7;

  // XCD-aware bijective decode: 512 blocks = 16 qt x 32 bh; XCD x gets bh 4x..4x+3
  const int id = blockIdx.x;
  const int bh = (id & 7) * 4 + ((id >> 3) & 3);
  const int qt = id >> 5;
  const int b = bh >> 4, h = bh & 15;
  const size_t bS = (size_t)b * SEQ;
  const int qw = qt * 128 + w * 16;             // wave's q base

  // Q fragments (held in regs): lane holds Q[q=qw+l15][e = ks*32 + l4*8 + j]
  short8 qf[2];
  {
    const char* qp = (const char*)Q + ((bS + qw + l15) * E_DIM + h * 64) * 2;
    qf[0] = *(const short8*)(qp + l4 * 16);
    qf[1] = *(const short8*)(qp + 64 + l4 * 16);
  }

  f32x4 zero = {0.f, 0.f, 0.f, 0.f};
  f32x4 oacc[4];                                 // O^T: d=df*16+l4*4+r, q=l15
#pragma unroll
  for (int i = 0; i < 4; ++i) oacc[i] = zero;
  float mrow = -1e30f, lrow = 0.f;

  // staging maps
  const int krow = l >> 3;                       // 0..7
  const int kcg  = (l & 7) ^ krow;               // inverse-swizzled source octet
  const char* vt_base = (const char*)Vt_g +
      ((size_t)(h * 64 + 8 * w + krow) * M_ROWS + bS) * 2 + (kcg << 4);

#define KSTAGE(KT, BUF)                                                        \
  gload_lds16((const char*)Kg +                                                \
                  ((bS + (size_t)(KT)*64 + 8*w + krow) * E_DIM + h*64 + kcg*8)*2, \
              (char*)Kl[BUF] + w * 1024)

#define VSTAGE(KT, BUF)                                                        \
  gload_lds16(vt_base + (size_t)(KT) * 128, (char*)Vl[BUF] + w * 1024)

  // prologue: tile 0
  KSTAGE(0, 0);
  VSTAGE(0, 0);
  __syncthreads();

  int cur = 0;
  constexpr int NT = SEQ / 64;
  for (int kt = 0; kt < NT; ++kt) {
    const bool more = (kt + 1 < NT);
    if (more) {
      KSTAGE(kt + 1, cur ^ 1);
      VSTAGE(kt + 1, cur ^ 1);
    }

    // ---- S^T = K Q^T : lane -> S[kv = nf*16 + l4*4 + r][q = qw + l15] ----
    f32x4 s[4];
    const char* kb = (const char*)Kl[cur];
#pragma unroll
    for (int nf = 0; nf < 4; ++nf) {
      const char* rowb = kb + (nf * 16 + l15) * 128;
      short8 k0 = *(const short8*)(rowb + ((l4 ^ l7) << 4));
      short8 k1 = *(const short8*)(rowb + (((4 + l4) ^ l7) << 4));
      f32x4 z = zero;
      z = __builtin_amdgcn_mfma_f32_16x16x32_bf16(k0, qf[0], z, 0, 0, 0);
      z = __builtin_amdgcn_mfma_f32_16x16x32_bf16(k1, qf[1], z, 0, 0, 0);
      s[nf] = z;
    }

    // ---- online softmax: per-lane scalar (q = l15; l4-groups hold kv quarters)
    float mx = s[0][0];
#pragma unroll
    for (int nf = 0; nf < 4; ++nf)
#pragma unroll
      for (int r = 0; r < 4; ++r) mx = fmaxf(mx, s[nf][r]);
    mx = fmaxf(mx, __shfl_xor(mx, 16));
    mx = fmaxf(mx, __shfl_xor(mx, 32));
    const float mnew = fmaxf(mrow, mx);
    const float fac = __builtin_amdgcn_exp2f(mrow - mnew);
    mrow = mnew;

    float pv[4][4];
    float rs = 0.f;
#pragma unroll
    for (int nf = 0; nf < 4; ++nf)
#pragma unroll
      for (int r = 0; r < 4; ++r) {
        float p = __builtin_amdgcn_exp2f(s[nf][r] - mnew);
        pv[nf][r] = p;
        rs += p;
      }
    rs += __shfl_xor(rs, 16);
    rs += __shfl_xor(rs, 32);
    lrow = lrow * fac + rs;

    // ---- P -> per-wave LDS, packed b64, chunk-XOR swizzle by q(&7)=l7 ----
    unsigned short* pw = Pl[w];
#pragma unroll
    for (int nf = 0; nf < 4; ++nf) {
      const int c = nf * 2 + (l4 >> 1);
      i32x2 pk;
      pk.x = cvtpk(pv[nf][0], pv[nf][1]);
      pk.y = cvtpk(pv[nf][2], pv[nf][3]);
      *(i32x2*)((char*)pw + l15 * 128 + ((c ^ l7) << 4) + ((l4 & 1) << 3)) = pk;
    }
    // B-fragments: P[q=l15][kv = ks*32 + l4*8 + j]
    short8 pf0 = *(const short8*)((const char*)pw + l15 * 128 + ((l4 ^ l7) << 4));
    short8 pf1 = *(const short8*)((const char*)pw + l15 * 128 + (((4 + l4) ^ l7) << 4));

    // ---- rescale + O^T += V^T P^T ----
#pragma unroll
    for (int df = 0; df < 4; ++df)
#pragma unroll
      for (int r = 0; r < 4; ++r) oacc[df][r] *= fac;

    const char* vb = (const char*)Vl[cur];
#pragma unroll
    for (int df = 0; df < 4; ++df) {
      const char* rowb = vb + (df * 16 + l15) * 128;
      short8 v0 = *(const short8*)(rowb + ((l4 ^ l7) << 4));
      short8 v1 = *(const short8*)(rowb + (((4 + l4) ^ l7) << 4));
      oacc[df] = __builtin_amdgcn_mfma_f32_16x16x32_bf16(v0, pf0, oacc[df], 0, 0, 0);
      oacc[df] = __builtin_amdgcn_mfma_f32_16x16x32_bf16(v1, pf1, oacc[df], 0, 0, 0);
    }

    __syncthreads();   // drains vmcnt+lgkmcnt: next buffers staged, cur free
    cur ^= 1;
  }
#undef KSTAGE
#undef VSTAGE

  // ---- epilogue: O[q = qw+l15][d = df*16 + l4*4 + r] ----
  const float rinv = __builtin_amdgcn_rcpf(lrow);
  unsigned short* orow = O + (bS + qw + l15) * E_DIM + h * 64;
#pragma unroll
  for (int df = 0; df < 4; ++df) {
    short4_t o4;
#pragma unroll
    for (int r = 0; r < 4; ++r) o4[r] = (short)f2bf(oacc[df][r] * rinv);
    *(short4_t*)(orow + df * 16 + l4 * 4) = o4;
  }
}

extern "C" void kernel_launch(void* const* d_in, const int* in_sizes, int n_in,
                              void* d_out, int out_size, void* d_ws, size_t ws_size,
                              hipStream_t stream) {
  const float* q_in = (const float*)d_in[0];
  const float* k_in = (const float*)d_in[1];
  const float* v_in = (const float*)d_in[2];
  const float* Wq = (const float*)d_in[3];
  const float* bq = (const float*)d_in[4];
  const float* Wk = (const float*)d_in[5];
  const float* bk = (const float*)d_in[6];
  const float* Wv = (const float*)d_in[7];
  const float* bv = (const float*)d_in[8];
  const float* Wo = (const float*)d_in[9];
  const float* bo = (const float*)d_in[10];

  char* ws = (char*)d_ws;
  const size_t XB = (size_t)M_ROWS * E_DIM * 2;   // 8 MiB
  const size_t WB = (size_t)E_DIM * E_DIM * 2;    // 2 MiB
  unsigned short* Xq  = (unsigned short*)(ws);
  unsigned short* Xk  = (unsigned short*)(ws + XB);
  unsigned short* Xv  = (unsigned short*)(ws + 2*XB);
  unsigned short* Wqb = (unsigned short*)(ws + 3*XB);
  unsigned short* Wkb = (unsigned short*)(ws + 3*XB + WB);
  unsigned short* Wvb = (unsigned short*)(ws + 3*XB + 2*WB);
  unsigned short* Wob = (unsigned short*)(ws + 3*XB + 3*WB);
  unsigned short* Qb  = (unsigned short*)(ws + 3*XB + 4*WB);
  unsigned short* Kb  = (unsigned short*)(ws + 4*XB + 4*WB);
  unsigned short* Vtg = (unsigned short*)(ws + 5*XB + 4*WB);  // V^T (e-major)
  unsigned short* Ob  = (unsigned short*)(ws + 6*XB + 4*WB);  // ends at 64 MiB

  const int nX8 = M_ROWS * E_DIM / 8;   // 524288
  const int nW8 = E_DIM * E_DIM / 8;    // 131072
  cvt3_f32_bf16<<<dim3(nX8/256, 3), 256, 0, stream>>>(q_in, k_in, v_in, Xq, Xk, Xv, nX8);
  cvt4_f32_bf16<<<dim3(nW8/256, 4), 256, 0, stream>>>(Wq, Wk, Wv, Wo, Wqb, Wkb, Wvb, Wob, nW8);

  const float qscale = 0.125f * 1.44269504088896340736f;  // scale * log2(e)
  gemm_qkv<<<dim3(512, 1, 3), 256, 0, stream>>>(Xq, Xk, Xv, Wqb, Wkb, Wvb,
                                                bq, bk, bv, Qb, Kb, Vtg, qscale);

  attn_fwd6<<<512, 512, 0, stream>>>(Qb, Kb, Vtg, Ob);   // 16 qt x 32 bh, xcd-swizzled

  dim3 ogrid(E_DIM/64, M_ROWS/128);        // 512 blocks
  gemm_o<<<ogrid, 256, 0, stream>>>(Ob, Wob, bo, (float*)d_out);
}

// Round 15
// 122.274 us; speedup vs baseline: 1.4309x; 1.0094x over previous
//
#include <hip/hip_runtime.h>
#include <stdint.h>

#define E_DIM 1024
#define N_HEADS 16
#define HEAD_D 64
#define BATCH 2
#define SEQ 2048
#define M_ROWS (BATCH*SEQ)   // 4096

typedef __attribute__((ext_vector_type(8))) short short8;
typedef __attribute__((ext_vector_type(4))) short short4_t;
typedef __attribute__((ext_vector_type(4))) float f32x4;
typedef __attribute__((ext_vector_type(4))) int i32x4;
typedef __attribute__((ext_vector_type(2))) int i32x2;

__device__ __forceinline__ unsigned short f2bf(float f) {
  uint32_t u = __float_as_uint(f);
  u += 0x7FFFu + ((u >> 16) & 1u);   // RTNE
  return (unsigned short)(u >> 16);
}

// async global->LDS, 16B per lane; LDS dest = wave-uniform base + lane*16
__device__ __forceinline__ void gload_lds16(const void* g, void* l) {
  __builtin_amdgcn_global_load_lds(
      (const __attribute__((address_space(1))) uint32_t*)(uintptr_t)g,
      (__attribute__((address_space(3))) uint32_t*)(uint32_t)(uintptr_t)l,
      16, 0, 0);
}

__device__ __forceinline__ int cvtpk(float lo, float hi) {
  int r;
  asm("v_cvt_pk_bf16_f32 %0, %1, %2" : "=v"(r) : "v"(lo), "v"(hi));
  return r;
}

__device__ __forceinline__ void cvt_body(const float* __restrict__ src,
                                         unsigned short* __restrict__ dst, int i) {
  f32x4 a = ((const f32x4*)src)[2*i];
  f32x4 b = ((const f32x4*)src)[2*i + 1];
  union { unsigned short us[8]; i32x4 v; } o;
  o.us[0] = f2bf(a[0]); o.us[1] = f2bf(a[1]);
  o.us[2] = f2bf(a[2]); o.us[3] = f2bf(a[3]);
  o.us[4] = f2bf(b[0]); o.us[5] = f2bf(b[1]);
  o.us[6] = f2bf(b[2]); o.us[7] = f2bf(b[3]);
  ((i32x4*)dst)[i] = o.v;
}

// All 7 f32->bf16 converts in ONE launch. Region sizes are powers of two:
// 3 x nX8 (2^19 items each) then 4 x nW8 (2^17 items each).
__global__ void cvt_all(const float* __restrict__ x0, const float* __restrict__ x1,
                        const float* __restrict__ x2,
                        const float* __restrict__ w0, const float* __restrict__ w1,
                        const float* __restrict__ w2, const float* __restrict__ w3,
                        unsigned short* __restrict__ dx0, unsigned short* __restrict__ dx1,
                        unsigned short* __restrict__ dx2,
                        unsigned short* __restrict__ dw0, unsigned short* __restrict__ dw1,
                        unsigned short* __restrict__ dw2, unsigned short* __restrict__ dw3) {
  const int i = blockIdx.x * blockDim.x + threadIdx.x;
  constexpr int NX8 = M_ROWS * E_DIM / 8;   // 2^19
  constexpr int NW8 = E_DIM * E_DIM / 8;    // 2^17
  if (i < 3 * NX8) {
    const int r = i >> 19, off = i & (NX8 - 1);
    const float* s = (r == 0) ? x0 : (r == 1) ? x1 : x2;
    unsigned short* d = (r == 0) ? dx0 : (r == 1) ? dx1 : dx2;
    cvt_body(s, d, off);
  } else {
    const int j = i - 3 * NX8;
    const int r = j >> 17, off = j & (NW8 - 1);
    const float* s = (r == 0) ? w0 : (r == 1) ? w1 : (r == 2) ? w2 : w3;
    unsigned short* d = (r == 0) ? dw0 : (r == 1) ? dw1 : (r == 2) ? dw2 : dw3;
    cvt_body(s, d, off);
  }
}

// ---------------------------------------------------------------------------
// 8-wave GEMM body (R7-verified 128x128 wave decode + R8-verified
// single-barrier double-buffer), runtime epilogue:
// C[m][n] = (sum_k A[m][k]*Bm[n][k] + bias[brow ? m : n]) * scale, bf16 out.
// ---------------------------------------------------------------------------
__device__ __forceinline__ void gemm_body_rt8(const unsigned short* __restrict__ A,
                                              const unsigned short* __restrict__ Bm,
                                              const float* __restrict__ bias,
                                              unsigned short* __restrict__ Cout,
                                              float scale, int bx, int by,
                                              int Nstr, bool brow) {
  constexpr int BM = 128, BN = 128, BK = 64, K = E_DIM;
  __shared__ __attribute__((aligned(16))) unsigned short Al[2][BM*BK];  // 16KB x2
  __shared__ __attribute__((aligned(16))) unsigned short Bl[2][BN*BK];  // 16KB x2
  const int tid  = threadIdx.x;
  const int lane = tid & 63, w = tid >> 6;    // 8 waves
  const int wm = w >> 2, wn = w & 3;          // wave tile 64x32, 2x4 waves
  const int l15 = lane & 15, l4 = lane >> 4, l7 = lane & 7;
  const int m0 = by * BM, n0 = bx * BN;
  const int jr = lane >> 3, jc = lane & 7;
  const int kcg = jc ^ jr;                    // inverse-swizzled source chunk

#define GSTAGE(KT, BUF)                                                        \
  do {                                                                         \
    _Pragma("unroll")                                                          \
    for (int t = 0; t < 2; ++t) {            /* A: 16 issues of 1KB, 2/wave */ \
      int ia = w*2 + t;                                                        \
      const char* src = (const char*)A +                                       \
          ((size_t)(m0 + ia*8 + jr)*K + (KT))*2 + (kcg << 4);                  \
      gload_lds16(src, (char*)Al[BUF] + ia*1024);                              \
    }                                                                          \
    _Pragma("unroll")                                                          \
    for (int t = 0; t < 2; ++t) {            /* B: 16 issues, 2/wave */        \
      int ib = w*2 + t;                                                        \
      const char* src = (const char*)Bm +                                      \
          ((size_t)(n0 + ib*8 + jr)*K + (KT))*2 + (kcg << 4);                  \
      gload_lds16(src, (char*)Bl[BUF] + ib*1024);                              \
    }                                                                          \
  } while (0)

  f32x4 zero = {0.f, 0.f, 0.f, 0.f};
  f32x4 acc[4][2];
  for (int i = 0; i < 4; ++i) for (int j = 0; j < 2; ++j) acc[i][j] = zero;

  GSTAGE(0, 0);
  __syncthreads();

  int cur = 0;
  const int NKT = K / BK;
  for (int kt = 0; kt < NKT; ++kt) {
    if (kt + 1 < NKT) GSTAGE((kt + 1) * BK, cur ^ 1);

#pragma unroll
    for (int ks = 0; ks < 2; ++ks) {
      const int sw = ((ks*4 + l4) ^ l7) << 4;
      short8 af[4], bf[2];
#pragma unroll
      for (int mf = 0; mf < 4; ++mf)
        af[mf] = *(const short8*)((const char*)Al[cur] + (wm*64 + mf*16 + l15)*128 + sw);
#pragma unroll
      for (int nf = 0; nf < 2; ++nf)
        bf[nf] = *(const short8*)((const char*)Bl[cur] + (wn*32 + nf*16 + l15)*128 + sw);
      __builtin_amdgcn_s_setprio(1);
#pragma unroll
      for (int mf = 0; mf < 4; ++mf)
#pragma unroll
        for (int nf = 0; nf < 2; ++nf)
          acc[mf][nf] = __builtin_amdgcn_mfma_f32_16x16x32_bf16(
              af[mf], bf[nf], acc[mf][nf], 0, 0, 0);
      __builtin_amdgcn_s_setprio(0);
    }

    __syncthreads();   // drains vmcnt: buf^1 staged; all reads of cur done
    cur ^= 1;
  }
#undef GSTAGE

#pragma unroll
  for (int nf = 0; nf < 2; ++nf) {
    const int col = n0 + wn*32 + nf*16 + l15;
    const float bcol = brow ? 0.f : bias[col];
#pragma unroll
    for (int mf = 0; mf < 4; ++mf) {
      const int rowb = m0 + wm*64 + mf*16 + l4*4;
#pragma unroll
      for (int r = 0; r < 4; ++r) {
        const float bv = brow ? bias[rowb + r] : bcol;
        float v = (acc[mf][nf][r] + bv) * scale;
        Cout[(size_t)(rowb + r)*Nstr + col] = f2bf(v);
      }
    }
  }
}

// Fused Q/K/V projections, 128x128 tiles: grid (256, 1, 3) = 768 blocks.
// z==2 computes V^T = Wv * Xv^T (operand swap): M=1024 (e), N=4096 (b*S+s).
__global__ __launch_bounds__(512, 4)
void gemm_qkv(const unsigned short* __restrict__ Xq, const unsigned short* __restrict__ Xk,
              const unsigned short* __restrict__ Xv,
              const unsigned short* __restrict__ Wq, const unsigned short* __restrict__ Wk,
              const unsigned short* __restrict__ Wv,
              const float* __restrict__ bq, const float* __restrict__ bk,
              const float* __restrict__ bv,
              unsigned short* __restrict__ Qb, unsigned short* __restrict__ Kb,
              unsigned short* __restrict__ Vt, float scale0) {
  const int z = blockIdx.z;
  const int idx = blockIdx.x;
  if (z == 2) {
    gemm_body_rt8(Wv, Xv, bv, Vt, 1.0f, idx & 31, idx >> 5, M_ROWS, true);
  } else {
    const unsigned short* A  = (z == 0) ? Xq : Xk;
    const unsigned short* Bm = (z == 0) ? Wq : Wk;
    const float* bias        = (z == 0) ? bq : bk;
    unsigned short* C        = (z == 0) ? Qb : Kb;
    const float scale        = (z == 0) ? scale0 : 1.0f;
    gemm_body_rt8(A, Bm, bias, C, scale, idx & 7, idx >> 3, E_DIM, false);
  }
}

// Output projection, f32 out to d_out (R8-verified 128x64 / 256 threads).
__global__ __launch_bounds__(256, 2)
void gemm_o(const unsigned short* __restrict__ A, const unsigned short* __restrict__ Bm,
            const float* __restrict__ bias, float* __restrict__ Cout) {
  constexpr int BM = 128, BN = 64, BK = 64, K = E_DIM, N = E_DIM;
  __shared__ __attribute__((aligned(16))) unsigned short Al[2][BM*BK];
  __shared__ __attribute__((aligned(16))) unsigned short Bl[2][BN*BK];
  const int tid  = threadIdx.x;
  const int lane = tid & 63, w = tid >> 6;
  const int wm = w >> 1, wn = w & 1;
  const int l15 = lane & 15, l4 = lane >> 4, l7 = lane & 7;
  const int m0 = blockIdx.y * BM, n0 = blockIdx.x * BN;
  const int jr = lane >> 3, jc = lane & 7;
  const int kcg = jc ^ jr;

#define GSTAGE(KT, BUF)                                                        \
  do {                                                                         \
    _Pragma("unroll")                                                          \
    for (int t = 0; t < 4; ++t) {                                              \
      int ia = w*4 + t;                                                        \
      const char* src = (const char*)A +                                       \
          ((size_t)(m0 + ia*8 + jr)*K + (KT))*2 + (kcg << 4);                  \
      gload_lds16(src, (char*)Al[BUF] + ia*1024);                              \
    }                                                                          \
    _Pragma("unroll")                                                          \
    for (int t = 0; t < 2; ++t) {                                              \
      int ib = w*2 + t;                                                        \
      const char* src = (const char*)Bm +                                      \
          ((size_t)(n0 + ib*8 + jr)*K + (KT))*2 + (kcg << 4);                  \
      gload_lds16(src, (char*)Bl[BUF] + ib*1024);                              \
    }                                                                          \
  } while (0)

  f32x4 zero = {0.f, 0.f, 0.f, 0.f};
  f32x4 acc[4][2];
  for (int i = 0; i < 4; ++i) for (int j = 0; j < 2; ++j) acc[i][j] = zero;

  GSTAGE(0, 0);
  __syncthreads();

  int cur = 0;
  const int NKT = K / BK;
  for (int kt = 0; kt < NKT; ++kt) {
    if (kt + 1 < NKT) GSTAGE((kt + 1) * BK, cur ^ 1);
#pragma unroll
    for (int ks = 0; ks < 2; ++ks) {
      const int sw = ((ks*4 + l4) ^ l7) << 4;
      short8 af[4], bf[2];
#pragma unroll
      for (int mf = 0; mf < 4; ++mf)
        af[mf] = *(const short8*)((const char*)Al[cur] + (wm*64 + mf*16 + l15)*128 + sw);
#pragma unroll
      for (int nf = 0; nf < 2; ++nf)
        bf[nf] = *(const short8*)((const char*)Bl[cur] + (wn*32 + nf*16 + l15)*128 + sw);
      __builtin_amdgcn_s_setprio(1);
#pragma unroll
      for (int mf = 0; mf < 4; ++mf)
#pragma unroll
        for (int nf = 0; nf < 2; ++nf)
          acc[mf][nf] = __builtin_amdgcn_mfma_f32_16x16x32_bf16(
              af[mf], bf[nf], acc[mf][nf], 0, 0, 0);
      __builtin_amdgcn_s_setprio(0);
    }
    __syncthreads();
    cur ^= 1;
  }
#undef GSTAGE

#pragma unroll
  for (int nf = 0; nf < 2; ++nf) {
    const int col = n0 + wn*32 + nf*16 + l15;
    const float bv = bias[col];
#pragma unroll
    for (int mf = 0; mf < 4; ++mf) {
      const int rowb = m0 + wm*64 + mf*16 + l4*4;
#pragma unroll
      for (int r = 0; r < 4; ++r)
        Cout[(size_t)(rowb + r)*N + col] = acc[mf][nf][r] + bv;
    }
  }
}

// ---------------------------------------------------------------------------
// Flash attention v6 (R13/R14-verified) + T5 setprio around MFMA clusters.
// 8 waves x 16 q, 512 blocks; V pre-transposed: (h*64+d)*M_ROWS + b*SEQ + s.
// ---------------------------------------------------------------------------
__global__ __launch_bounds__(512, 2)
void attn_fwd6(const unsigned short* __restrict__ Q,
               const unsigned short* __restrict__ Kg,
               const unsigned short* __restrict__ Vt_g,
               unsigned short* __restrict__ O) {
  __shared__ __attribute__((aligned(16))) unsigned short Kl[2][4096];
  __shared__ __attribute__((aligned(16))) unsigned short Vl[2][4096];
  __shared__ __attribute__((aligned(16))) unsigned short Pl[8][1024];

  const int tid = threadIdx.x;
  const int l = tid & 63, w = tid >> 6;
  const int l15 = l & 15, l4 = l >> 4, l7 = l & 7;

  // XCD-aware bijective decode: 512 blocks = 16 qt x 32 bh; XCD x gets bh 4x..4x+3
  const int id = blockIdx.x;
  const int bh = (id & 7) * 4 + ((id >> 3) & 3);
  const int qt = id >> 5;
  const int b = bh >> 4, h = bh & 15;
  const size_t bS = (size_t)b * SEQ;
  const int qw = qt * 128 + w * 16;             // wave's q base

  // Q fragments (held in regs): lane holds Q[q=qw+l15][e = ks*32 + l4*8 + j]
  short8 qf[2];
  {
    const char* qp = (const char*)Q + ((bS + qw + l15) * E_DIM + h * 64) * 2;
    qf[0] = *(const short8*)(qp + l4 * 16);
    qf[1] = *(const short8*)(qp + 64 + l4 * 16);
  }

  f32x4 zero = {0.f, 0.f, 0.f, 0.f};
  f32x4 oacc[4];                                 // O^T: d=df*16+l4*4+r, q=l15
#pragma unroll
  for (int i = 0; i < 4; ++i) oacc[i] = zero;
  float mrow = -1e30f, lrow = 0.f;

  // staging maps
  const int krow = l >> 3;                       // 0..7
  const int kcg  = (l & 7) ^ krow;               // inverse-swizzled source octet
  const char* vt_base = (const char*)Vt_g +
      ((size_t)(h * 64 + 8 * w + krow) * M_ROWS + bS) * 2 + (kcg << 4);

#define KSTAGE(KT, BUF)                                                        \
  gload_lds16((const char*)Kg +                                                \
                  ((bS + (size_t)(KT)*64 + 8*w + krow) * E_DIM + h*64 + kcg*8)*2, \
              (char*)Kl[BUF] + w * 1024)

#define VSTAGE(KT, BUF)                                                        \
  gload_lds16(vt_base + (size_t)(KT) * 128, (char*)Vl[BUF] + w * 1024)

  // prologue: tile 0
  KSTAGE(0, 0);
  VSTAGE(0, 0);
  __syncthreads();

  int cur = 0;
  constexpr int NT = SEQ / 64;
  for (int kt = 0; kt < NT; ++kt) {
    const bool more = (kt + 1 < NT);
    if (more) {
      KSTAGE(kt + 1, cur ^ 1);
      VSTAGE(kt + 1, cur ^ 1);
    }

    // ---- S^T = K Q^T : lane -> S[kv = nf*16 + l4*4 + r][q = qw + l15] ----
    f32x4 s[4];
    const char* kb = (const char*)Kl[cur];
    __builtin_amdgcn_s_setprio(1);
#pragma unroll
    for (int nf = 0; nf < 4; ++nf) {
      const char* rowb = kb + (nf * 16 + l15) * 128;
      short8 k0 = *(const short8*)(rowb + ((l4 ^ l7) << 4));
      short8 k1 = *(const short8*)(rowb + (((4 + l4) ^ l7) << 4));
      f32x4 z = zero;
      z = __builtin_amdgcn_mfma_f32_16x16x32_bf16(k0, qf[0], z, 0, 0, 0);
      z = __builtin_amdgcn_mfma_f32_16x16x32_bf16(k1, qf[1], z, 0, 0, 0);
      s[nf] = z;
    }
    __builtin_amdgcn_s_setprio(0);

    // ---- online softmax: per-lane scalar (q = l15; l4-groups hold kv quarters)
    float mx = s[0][0];
#pragma unroll
    for (int nf = 0; nf < 4; ++nf)
#pragma unroll
      for (int r = 0; r < 4; ++r) mx = fmaxf(mx, s[nf][r]);
    mx = fmaxf(mx, __shfl_xor(mx, 16));
    mx = fmaxf(mx, __shfl_xor(mx, 32));
    const float mnew = fmaxf(mrow, mx);
    const float fac = __builtin_amdgcn_exp2f(mrow - mnew);
    mrow = mnew;

    float pv[4][4];
    float rs = 0.f;
#pragma unroll
    for (int nf = 0; nf < 4; ++nf)
#pragma unroll
      for (int r = 0; r < 4; ++r) {
        float p = __builtin_amdgcn_exp2f(s[nf][r] - mnew);
        pv[nf][r] = p;
        rs += p;
      }
    rs += __shfl_xor(rs, 16);
    rs += __shfl_xor(rs, 32);
    lrow = lrow * fac + rs;

    // ---- P -> per-wave LDS, packed b64, chunk-XOR swizzle by q(&7)=l7 ----
    unsigned short* pw = Pl[w];
#pragma unroll
    for (int nf = 0; nf < 4; ++nf) {
      const int c = nf * 2 + (l4 >> 1);
      i32x2 pk;
      pk.x = cvtpk(pv[nf][0], pv[nf][1]);
      pk.y = cvtpk(pv[nf][2], pv[nf][3]);
      *(i32x2*)((char*)pw + l15 * 128 + ((c ^ l7) << 4) + ((l4 & 1) << 3)) = pk;
    }
    // B-fragments: P[q=l15][kv = ks*32 + l4*8 + j]
    short8 pf0 = *(const short8*)((const char*)pw + l15 * 128 + ((l4 ^ l7) << 4));
    short8 pf1 = *(const short8*)((const char*)pw + l15 * 128 + (((4 + l4) ^ l7) << 4));

    // ---- rescale + O^T += V^T P^T ----
#pragma unroll
    for (int df = 0; df < 4; ++df)
#pragma unroll
      for (int r = 0; r < 4; ++r) oacc[df][r] *= fac;

    const char* vb = (const char*)Vl[cur];
    __builtin_amdgcn_s_setprio(1);
#pragma unroll
    for (int df = 0; df < 4; ++df) {
      const char* rowb = vb + (df * 16 + l15) * 128;
      short8 v0 = *(const short8*)(rowb + ((l4 ^ l7) << 4));
      short8 v1 = *(const short8*)(rowb + (((4 + l4) ^ l7) << 4));
      oacc[df] = __builtin_amdgcn_mfma_f32_16x16x32_bf16(v0, pf0, oacc[df], 0, 0, 0);
      oacc[df] = __builtin_amdgcn_mfma_f32_16x16x32_bf16(v1, pf1, oacc[df], 0, 0, 0);
    }
    __builtin_amdgcn_s_setprio(0);

    __syncthreads();   // drains vmcnt+lgkmcnt: next buffers staged, cur free
    cur ^= 1;
  }
#undef KSTAGE
#undef VSTAGE

  // ---- epilogue: O[q = qw+l15][d = df*16 + l4*4 + r] ----
  const float rinv = __builtin_amdgcn_rcpf(lrow);
  unsigned short* orow = O + (bS + qw + l15) * E_DIM + h * 64;
#pragma unroll
  for (int df = 0; df < 4; ++df) {
    short4_t o4;
#pragma unroll
    for (int r = 0; r < 4; ++r) o4[r] = (short)f2bf(oacc[df][r] * rinv);
    *(short4_t*)(orow + df * 16 + l4 * 4) = o4;
  }
}

extern "C" void kernel_launch(void* const* d_in, const int* in_sizes, int n_in,
                              void* d_out, int out_size, void* d_ws, size_t ws_size,
                              hipStream_t stream) {
  const float* q_in = (const float*)d_in[0];
  const float* k_in = (const float*)d_in[1];
  const float* v_in = (const float*)d_in[2];
  const float* Wq = (const float*)d_in[3];
  const float* bq = (const float*)d_in[4];
  const float* Wk = (const float*)d_in[5];
  const float* bk = (const float*)d_in[6];
  const float* Wv = (const float*)d_in[7];
  const float* bv = (const float*)d_in[8];
  const float* Wo = (const float*)d_in[9];
  const float* bo = (const float*)d_in[10];

  char* ws = (char*)d_ws;
  const size_t XB = (size_t)M_ROWS * E_DIM * 2;   // 8 MiB
  const size_t WB = (size_t)E_DIM * E_DIM * 2;    // 2 MiB
  unsigned short* Xq  = (unsigned short*)(ws);
  unsigned short* Xk  = (unsigned short*)(ws + XB);
  unsigned short* Xv  = (unsigned short*)(ws + 2*XB);
  unsigned short* Wqb = (unsigned short*)(ws + 3*XB);
  unsigned short* Wkb = (unsigned short*)(ws + 3*XB + WB);
  unsigned short* Wvb = (unsigned short*)(ws + 3*XB + 2*WB);
  unsigned short* Wob = (unsigned short*)(ws + 3*XB + 3*WB);
  unsigned short* Qb  = (unsigned short*)(ws + 3*XB + 4*WB);
  unsigned short* Kb  = (unsigned short*)(ws + 4*XB + 4*WB);
  unsigned short* Vtg = (unsigned short*)(ws + 5*XB + 4*WB);  // V^T (e-major)
  unsigned short* Ob  = (unsigned short*)(ws + 6*XB + 4*WB);  // ends at 64 MiB

  // one fused convert launch: (3*2^19 + 4*2^17)/256 = 8192 blocks
  cvt_all<<<8192, 256, 0, stream>>>(q_in, k_in, v_in, Wq, Wk, Wv, Wo,
                                    Xq, Xk, Xv, Wqb, Wkb, Wvb, Wob);

  const float qscale = 0.125f * 1.44269504088896340736f;  // scale * log2(e)
  gemm_qkv<<<dim3(256, 1, 3), 512, 0, stream>>>(Xq, Xk, Xv, Wqb, Wkb, Wvb,
                                                bq, bk, bv, Qb, Kb, Vtg, qscale);

  attn_fwd6<<<512, 512, 0, stream>>>(Qb, Kb, Vtg, Ob);   // 16 qt x 32 bh, xcd-swizzled

  dim3 ogrid(E_DIM/64, M_ROWS/128);        // 512 blocks
  gemm_o<<<ogrid, 256, 0, stream>>>(Ob, Wob, bo, (float*)d_out);
}

// Round 16
// 121.906 us; speedup vs baseline: 1.4352x; 1.0030x over previous
//
#include <hip/hip_runtime.h>
#include <stdint.h>

#define E_DIM 1024
#define N_HEADS 16
#define HEAD_D 64
#define BATCH 2
#define SEQ 2048
#define M_ROWS (BATCH*SEQ)   // 4096

typedef __attribute__((ext_vector_type(8))) short short8;
typedef __attribute__((ext_vector_type(4))) short short4_t;
typedef __attribute__((ext_vector_type(4))) float f32x4;
typedef __attribute__((ext_vector_type(4))) int i32x4;
typedef __attribute__((ext_vector_type(2))) int i32x2;

__device__ __forceinline__ unsigned short f2bf(float f) {
  uint32_t u = __float_as_uint(f);
  u += 0x7FFFu + ((u >> 16) & 1u);   // RTNE
  return (unsigned short)(u >> 16);
}

// async global->LDS, 16B per lane; LDS dest = wave-uniform base + lane*16
__device__ __forceinline__ void gload_lds16(const void* g, void* l) {
  __builtin_amdgcn_global_load_lds(
      (const __attribute__((address_space(1))) uint32_t*)(uintptr_t)g,
      (__attribute__((address_space(3))) uint32_t*)(uint32_t)(uintptr_t)l,
      16, 0, 0);
}

__device__ __forceinline__ int cvtpk(float lo, float hi) {
  int r;
  asm("v_cvt_pk_bf16_f32 %0, %1, %2" : "=v"(r) : "v"(lo), "v"(hi));
  return r;
}

__device__ __forceinline__ void cvt_body(const float* __restrict__ src,
                                         unsigned short* __restrict__ dst, int i) {
  f32x4 a = ((const f32x4*)src)[2*i];
  f32x4 b = ((const f32x4*)src)[2*i + 1];
  union { unsigned short us[8]; i32x4 v; } o;
  o.us[0] = f2bf(a[0]); o.us[1] = f2bf(a[1]);
  o.us[2] = f2bf(a[2]); o.us[3] = f2bf(a[3]);
  o.us[4] = f2bf(b[0]); o.us[5] = f2bf(b[1]);
  o.us[6] = f2bf(b[2]); o.us[7] = f2bf(b[3]);
  ((i32x4*)dst)[i] = o.v;
}

// All 7 f32->bf16 converts in ONE launch (R15-verified).
__global__ void cvt_all(const float* __restrict__ x0, const float* __restrict__ x1,
                        const float* __restrict__ x2,
                        const float* __restrict__ w0, const float* __restrict__ w1,
                        const float* __restrict__ w2, const float* __restrict__ w3,
                        unsigned short* __restrict__ dx0, unsigned short* __restrict__ dx1,
                        unsigned short* __restrict__ dx2,
                        unsigned short* __restrict__ dw0, unsigned short* __restrict__ dw1,
                        unsigned short* __restrict__ dw2, unsigned short* __restrict__ dw3) {
  const int i = blockIdx.x * blockDim.x + threadIdx.x;
  constexpr int NX8 = M_ROWS * E_DIM / 8;   // 2^19
  constexpr int NW8 = E_DIM * E_DIM / 8;    // 2^17
  if (i < 3 * NX8) {
    const int r = i >> 19, off = i & (NX8 - 1);
    const float* s = (r == 0) ? x0 : (r == 1) ? x1 : x2;
    unsigned short* d = (r == 0) ? dx0 : (r == 1) ? dx1 : dx2;
    cvt_body(s, d, off);
  } else {
    const int j = i - 3 * NX8;
    const int r = j >> 17, off = j & (NW8 - 1);
    const float* s = (r == 0) ? w0 : (r == 1) ? w1 : (r == 2) ? w2 : w3;
    unsigned short* d = (r == 0) ? dw0 : (r == 1) ? dw1 : (r == 2) ? dw2 : dw3;
    cvt_body(s, d, off);
  }
}

// ---------------------------------------------------------------------------
// 8-wave GEMM body (R15-verified), runtime epilogue.
// ---------------------------------------------------------------------------
__device__ __forceinline__ void gemm_body_rt8(const unsigned short* __restrict__ A,
                                              const unsigned short* __restrict__ Bm,
                                              const float* __restrict__ bias,
                                              unsigned short* __restrict__ Cout,
                                              float scale, int bx, int by,
                                              int Nstr, bool brow) {
  constexpr int BM = 128, BN = 128, BK = 64, K = E_DIM;
  __shared__ __attribute__((aligned(16))) unsigned short Al[2][BM*BK];
  __shared__ __attribute__((aligned(16))) unsigned short Bl[2][BN*BK];
  const int tid  = threadIdx.x;
  const int lane = tid & 63, w = tid >> 6;
  const int wm = w >> 2, wn = w & 3;
  const int l15 = lane & 15, l4 = lane >> 4, l7 = lane & 7;
  const int m0 = by * BM, n0 = bx * BN;
  const int jr = lane >> 3, jc = lane & 7;
  const int kcg = jc ^ jr;

#define GSTAGE(KT, BUF)                                                        \
  do {                                                                         \
    _Pragma("unroll")                                                          \
    for (int t = 0; t < 2; ++t) {                                              \
      int ia = w*2 + t;                                                        \
      const char* src = (const char*)A +                                       \
          ((size_t)(m0 + ia*8 + jr)*K + (KT))*2 + (kcg << 4);                  \
      gload_lds16(src, (char*)Al[BUF] + ia*1024);                              \
    }                                                                          \
    _Pragma("unroll")                                                          \
    for (int t = 0; t < 2; ++t) {                                              \
      int ib = w*2 + t;                                                        \
      const char* src = (const char*)Bm +                                      \
          ((size_t)(n0 + ib*8 + jr)*K + (KT))*2 + (kcg << 4);                  \
      gload_lds16(src, (char*)Bl[BUF] + ib*1024);                              \
    }                                                                          \
  } while (0)

  f32x4 zero = {0.f, 0.f, 0.f, 0.f};
  f32x4 acc[4][2];
  for (int i = 0; i < 4; ++i) for (int j = 0; j < 2; ++j) acc[i][j] = zero;

  GSTAGE(0, 0);
  __syncthreads();

  int cur = 0;
  const int NKT = K / BK;
  for (int kt = 0; kt < NKT; ++kt) {
    if (kt + 1 < NKT) GSTAGE((kt + 1) * BK, cur ^ 1);

#pragma unroll
    for (int ks = 0; ks < 2; ++ks) {
      const int sw = ((ks*4 + l4) ^ l7) << 4;
      short8 af[4], bf[2];
#pragma unroll
      for (int mf = 0; mf < 4; ++mf)
        af[mf] = *(const short8*)((const char*)Al[cur] + (wm*64 + mf*16 + l15)*128 + sw);
#pragma unroll
      for (int nf = 0; nf < 2; ++nf)
        bf[nf] = *(const short8*)((const char*)Bl[cur] + (wn*32 + nf*16 + l15)*128 + sw);
      __builtin_amdgcn_s_setprio(1);
#pragma unroll
      for (int mf = 0; mf < 4; ++mf)
#pragma unroll
        for (int nf = 0; nf < 2; ++nf)
          acc[mf][nf] = __builtin_amdgcn_mfma_f32_16x16x32_bf16(
              af[mf], bf[nf], acc[mf][nf], 0, 0, 0);
      __builtin_amdgcn_s_setprio(0);
    }

    __syncthreads();
    cur ^= 1;
  }
#undef GSTAGE

#pragma unroll
  for (int nf = 0; nf < 2; ++nf) {
    const int col = n0 + wn*32 + nf*16 + l15;
    const float bcol = brow ? 0.f : bias[col];
#pragma unroll
    for (int mf = 0; mf < 4; ++mf) {
      const int rowb = m0 + wm*64 + mf*16 + l4*4;
#pragma unroll
      for (int r = 0; r < 4; ++r) {
        const float bv = brow ? bias[rowb + r] : bcol;
        float v = (acc[mf][nf][r] + bv) * scale;
        Cout[(size_t)(rowb + r)*Nstr + col] = f2bf(v);
      }
    }
  }
}

// Fused Q/K/V projections, 128x128 tiles: grid (256, 1, 3).
__global__ __launch_bounds__(512, 4)
void gemm_qkv(const unsigned short* __restrict__ Xq, const unsigned short* __restrict__ Xk,
              const unsigned short* __restrict__ Xv,
              const unsigned short* __restrict__ Wq, const unsigned short* __restrict__ Wk,
              const unsigned short* __restrict__ Wv,
              const float* __restrict__ bq, const float* __restrict__ bk,
              const float* __restrict__ bv,
              unsigned short* __restrict__ Qb, unsigned short* __restrict__ Kb,
              unsigned short* __restrict__ Vt, float scale0) {
  const int z = blockIdx.z;
  const int idx = blockIdx.x;
  if (z == 2) {
    gemm_body_rt8(Wv, Xv, bv, Vt, 1.0f, idx & 31, idx >> 5, M_ROWS, true);
  } else {
    const unsigned short* A  = (z == 0) ? Xq : Xk;
    const unsigned short* Bm = (z == 0) ? Wq : Wk;
    const float* bias        = (z == 0) ? bq : bk;
    unsigned short* C        = (z == 0) ? Qb : Kb;
    const float scale        = (z == 0) ? scale0 : 1.0f;
    gemm_body_rt8(A, Bm, bias, C, scale, idx & 7, idx >> 3, E_DIM, false);
  }
}

// Output projection, f32 out to d_out (R8-verified 128x64 / 256 threads).
__global__ __launch_bounds__(256, 2)
void gemm_o(const unsigned short* __restrict__ A, const unsigned short* __restrict__ Bm,
            const float* __restrict__ bias, float* __restrict__ Cout) {
  constexpr int BM = 128, BN = 64, BK = 64, K = E_DIM, N = E_DIM;
  __shared__ __attribute__((aligned(16))) unsigned short Al[2][BM*BK];
  __shared__ __attribute__((aligned(16))) unsigned short Bl[2][BN*BK];
  const int tid  = threadIdx.x;
  const int lane = tid & 63, w = tid >> 6;
  const int wm = w >> 1, wn = w & 1;
  const int l15 = lane & 15, l4 = lane >> 4, l7 = lane & 7;
  const int m0 = blockIdx.y * BM, n0 = blockIdx.x * BN;
  const int jr = lane >> 3, jc = lane & 7;
  const int kcg = jc ^ jr;

#define GSTAGE(KT, BUF)                                                        \
  do {                                                                         \
    _Pragma("unroll")                                                          \
    for (int t = 0; t < 4; ++t) {                                              \
      int ia = w*4 + t;                                                        \
      const char* src = (const char*)A +                                       \
          ((size_t)(m0 + ia*8 + jr)*K + (KT))*2 + (kcg << 4);                  \
      gload_lds16(src, (char*)Al[BUF] + ia*1024);                              \
    }                                                                          \
    _Pragma("unroll")                                                          \
    for (int t = 0; t < 2; ++t) {                                              \
      int ib = w*2 + t;                                                        \
      const char* src = (const char*)Bm +                                      \
          ((size_t)(n0 + ib*8 + jr)*K + (KT))*2 + (kcg << 4);                  \
      gload_lds16(src, (char*)Bl[BUF] + ib*1024);                              \
    }                                                                          \
  } while (0)

  f32x4 zero = {0.f, 0.f, 0.f, 0.f};
  f32x4 acc[4][2];
  for (int i = 0; i < 4; ++i) for (int j = 0; j < 2; ++j) acc[i][j] = zero;

  GSTAGE(0, 0);
  __syncthreads();

  int cur = 0;
  const int NKT = K / BK;
  for (int kt = 0; kt < NKT; ++kt) {
    if (kt + 1 < NKT) GSTAGE((kt + 1) * BK, cur ^ 1);
#pragma unroll
    for (int ks = 0; ks < 2; ++ks) {
      const int sw = ((ks*4 + l4) ^ l7) << 4;
      short8 af[4], bf[2];
#pragma unroll
      for (int mf = 0; mf < 4; ++mf)
        af[mf] = *(const short8*)((const char*)Al[cur] + (wm*64 + mf*16 + l15)*128 + sw);
#pragma unroll
      for (int nf = 0; nf < 2; ++nf)
        bf[nf] = *(const short8*)((const char*)Bl[cur] + (wn*32 + nf*16 + l15)*128 + sw);
      __builtin_amdgcn_s_setprio(1);
#pragma unroll
      for (int mf = 0; mf < 4; ++mf)
#pragma unroll
        for (int nf = 0; nf < 2; ++nf)
          acc[mf][nf] = __builtin_amdgcn_mfma_f32_16x16x32_bf16(
              af[mf], bf[nf], acc[mf][nf], 0, 0, 0);
      __builtin_amdgcn_s_setprio(0);
    }
    __syncthreads();
    cur ^= 1;
  }
#undef GSTAGE

#pragma unroll
  for (int nf = 0; nf < 2; ++nf) {
    const int col = n0 + wn*32 + nf*16 + l15;
    const float bv = bias[col];
#pragma unroll
    for (int mf = 0; mf < 4; ++mf) {
      const int rowb = m0 + wm*64 + mf*16 + l4*4;
#pragma unroll
      for (int r = 0; r < 4; ++r)
        Cout[(size_t)(rowb + r)*N + col] = acc[mf][nf][r] + bv;
    }
  }
}

// ---------------------------------------------------------------------------
// Flash attention v7: 8 waves x 2 q-groups x 16 rows = 256-q tile, 256 blocks.
// K-frags and V-frags read from LDS ONCE per tile, shared by both q-groups
// (halves the dominant LDS-read cost per q-row). Group loop = R9-verified
// attn_fwd4 mechanics; staging = R14-verified 1-gload/wave K/V^T pattern.
// Separate P buffer per (wave, group): LDS total 64KB, 1 block/CU.
// ---------------------------------------------------------------------------
__global__ __launch_bounds__(512, 2)
void attn_fwd7(const unsigned short* __restrict__ Q,
               const unsigned short* __restrict__ Kg,
               const unsigned short* __restrict__ Vt_g,
               unsigned short* __restrict__ O) {
  __shared__ __attribute__((aligned(16))) unsigned short Kl[2][4096];
  __shared__ __attribute__((aligned(16))) unsigned short Vl[2][4096];
  __shared__ __attribute__((aligned(16))) unsigned short Pl[8][2][1024];

  const int tid = threadIdx.x;
  const int l = tid & 63, w = tid >> 6;
  const int l15 = l & 15, l4 = l >> 4, l7 = l & 7;

  // XCD-aware bijective decode: 256 blocks = 8 qt x 32 bh; XCD x gets bh 4x..4x+3
  const int id = blockIdx.x;
  const int bh = (id & 7) * 4 + ((id >> 3) & 3);
  const int qt = id >> 5;                       // 0..7
  const int b = bh >> 4, h = bh & 15;
  const size_t bS = (size_t)b * SEQ;
  const int qw = qt * 256 + w * 32;             // wave's q base (32 rows)

  // Q fragments, 2 groups: lane holds Q[q = qw + g*16 + l15][e = ks*32+l4*8+j]
  short8 qf[2][2];
#pragma unroll
  for (int g = 0; g < 2; ++g) {
    const char* qp = (const char*)Q + ((bS + qw + g*16 + l15) * E_DIM + h * 64) * 2;
    qf[g][0] = *(const short8*)(qp + l4 * 16);
    qf[g][1] = *(const short8*)(qp + 64 + l4 * 16);
  }

  f32x4 zero = {0.f, 0.f, 0.f, 0.f};
  f32x4 oacc[2][4];                              // O^T: d=df*16+l4*4+r, q=l15
#pragma unroll
  for (int g = 0; g < 2; ++g)
#pragma unroll
    for (int i = 0; i < 4; ++i) oacc[g][i] = zero;
  float mrow[2] = {-1e30f, -1e30f}, lrow[2] = {0.f, 0.f};

  // staging maps (R14-verified)
  const int krow = l >> 3;                       // 0..7
  const int kcg  = (l & 7) ^ krow;               // inverse-swizzled source octet
  const char* vt_base = (const char*)Vt_g +
      ((size_t)(h * 64 + 8 * w + krow) * M_ROWS + bS) * 2 + (kcg << 4);

#define KSTAGE(KT, BUF)                                                        \
  gload_lds16((const char*)Kg +                                                \
                  ((bS + (size_t)(KT)*64 + 8*w + krow) * E_DIM + h*64 + kcg*8)*2, \
              (char*)Kl[BUF] + w * 1024)

#define VSTAGE(KT, BUF)                                                        \
  gload_lds16(vt_base + (size_t)(KT) * 128, (char*)Vl[BUF] + w * 1024)

  // prologue: tile 0
  KSTAGE(0, 0);
  VSTAGE(0, 0);
  __syncthreads();

  int cur = 0;
  constexpr int NT = SEQ / 64;
  for (int kt = 0; kt < NT; ++kt) {
    const bool more = (kt + 1 < NT);
    if (more) {
      KSTAGE(kt + 1, cur ^ 1);
      VSTAGE(kt + 1, cur ^ 1);
    }

    // ---- K fragments ONCE (shared by both q-groups) ----
    short8 kf[8];
    {
      const char* kb = (const char*)Kl[cur];
#pragma unroll
      for (int nf = 0; nf < 4; ++nf) {
        const char* rowb = kb + (nf * 16 + l15) * 128;
        kf[nf*2]     = *(const short8*)(rowb + ((l4 ^ l7) << 4));
        kf[nf*2 + 1] = *(const short8*)(rowb + (((4 + l4) ^ l7) << 4));
      }
    }

    // ---- per-group: S^T, softmax, P round-trip -> B-fragments ----
    short8 pf[2][2];
#pragma unroll
    for (int g = 0; g < 2; ++g) {
      f32x4 s[4];
      __builtin_amdgcn_s_setprio(1);
#pragma unroll
      for (int nf = 0; nf < 4; ++nf) {
        f32x4 z = zero;
        z = __builtin_amdgcn_mfma_f32_16x16x32_bf16(kf[nf*2],     qf[g][0], z, 0, 0, 0);
        z = __builtin_amdgcn_mfma_f32_16x16x32_bf16(kf[nf*2 + 1], qf[g][1], z, 0, 0, 0);
        s[nf] = z;
      }
      __builtin_amdgcn_s_setprio(0);

      float mx = s[0][0];
#pragma unroll
      for (int nf = 0; nf < 4; ++nf)
#pragma unroll
        for (int r = 0; r < 4; ++r) mx = fmaxf(mx, s[nf][r]);
      mx = fmaxf(mx, __shfl_xor(mx, 16));
      mx = fmaxf(mx, __shfl_xor(mx, 32));
      const float mnew = fmaxf(mrow[g], mx);
      const float fac = __builtin_amdgcn_exp2f(mrow[g] - mnew);
      mrow[g] = mnew;

      float pv[4][4];
      float rs = 0.f;
#pragma unroll
      for (int nf = 0; nf < 4; ++nf)
#pragma unroll
        for (int r = 0; r < 4; ++r) {
          float p = __builtin_amdgcn_exp2f(s[nf][r] - mnew);
          pv[nf][r] = p;
          rs += p;
        }
      rs += __shfl_xor(rs, 16);
      rs += __shfl_xor(rs, 32);
      lrow[g] = lrow[g] * fac + rs;

#pragma unroll
      for (int df = 0; df < 4; ++df)
#pragma unroll
        for (int r = 0; r < 4; ++r) oacc[g][df][r] *= fac;

      // P -> per-(wave,group) LDS, packed b64, chunk-XOR swizzle by q(&7)=l7
      char* pw = (char*)&Pl[w][g][0];
#pragma unroll
      for (int nf = 0; nf < 4; ++nf) {
        const int c = nf * 2 + (l4 >> 1);
        i32x2 pk;
        pk.x = cvtpk(pv[nf][0], pv[nf][1]);
        pk.y = cvtpk(pv[nf][2], pv[nf][3]);
        *(i32x2*)(pw + l15 * 128 + ((c ^ l7) << 4) + ((l4 & 1) << 3)) = pk;
      }
      pf[g][0] = *(const short8*)(pw + l15 * 128 + ((l4 ^ l7) << 4));
      pf[g][1] = *(const short8*)(pw + l15 * 128 + (((4 + l4) ^ l7) << 4));
    }

    // ---- V fragments ONCE; PV for both groups ----
    {
      const char* vbuf = (const char*)Vl[cur];
      __builtin_amdgcn_s_setprio(1);
#pragma unroll
      for (int df = 0; df < 4; ++df) {
        const char* rowb = vbuf + (df * 16 + l15) * 128;
        short8 v0 = *(const short8*)(rowb + ((l4 ^ l7) << 4));
        short8 v1 = *(const short8*)(rowb + (((4 + l4) ^ l7) << 4));
#pragma unroll
        for (int g = 0; g < 2; ++g) {
          oacc[g][df] = __builtin_amdgcn_mfma_f32_16x16x32_bf16(v0, pf[g][0], oacc[g][df], 0, 0, 0);
          oacc[g][df] = __builtin_amdgcn_mfma_f32_16x16x32_bf16(v1, pf[g][1], oacc[g][df], 0, 0, 0);
        }
      }
      __builtin_amdgcn_s_setprio(0);
    }

    __syncthreads();   // drains vmcnt+lgkmcnt: next buffers staged, cur free
    cur ^= 1;
  }
#undef KSTAGE
#undef VSTAGE

  // ---- epilogue: O[q = qw + g*16 + l15][d = df*16 + l4*4 + r] ----
#pragma unroll
  for (int g = 0; g < 2; ++g) {
    const float rinv = __builtin_amdgcn_rcpf(lrow[g]);
    unsigned short* orow = O + (bS + qw + g*16 + l15) * E_DIM + h * 64;
#pragma unroll
    for (int df = 0; df < 4; ++df) {
      short4_t o4;
#pragma unroll
      for (int r = 0; r < 4; ++r) o4[r] = (short)f2bf(oacc[g][df][r] * rinv);
      *(short4_t*)(orow + df * 16 + l4 * 4) = o4;
    }
  }
}

extern "C" void kernel_launch(void* const* d_in, const int* in_sizes, int n_in,
                              void* d_out, int out_size, void* d_ws, size_t ws_size,
                              hipStream_t stream) {
  const float* q_in = (const float*)d_in[0];
  const float* k_in = (const float*)d_in[1];
  const float* v_in = (const float*)d_in[2];
  const float* Wq = (const float*)d_in[3];
  const float* bq = (const float*)d_in[4];
  const float* Wk = (const float*)d_in[5];
  const float* bk = (const float*)d_in[6];
  const float* Wv = (const float*)d_in[7];
  const float* bv = (const float*)d_in[8];
  const float* Wo = (const float*)d_in[9];
  const float* bo = (const float*)d_in[10];

  char* ws = (char*)d_ws;
  const size_t XB = (size_t)M_ROWS * E_DIM * 2;   // 8 MiB
  const size_t WB = (size_t)E_DIM * E_DIM * 2;    // 2 MiB
  unsigned short* Xq  = (unsigned short*)(ws);
  unsigned short* Xk  = (unsigned short*)(ws + XB);
  unsigned short* Xv  = (unsigned short*)(ws + 2*XB);
  unsigned short* Wqb = (unsigned short*)(ws + 3*XB);
  unsigned short* Wkb = (unsigned short*)(ws + 3*XB + WB);
  unsigned short* Wvb = (unsigned short*)(ws + 3*XB + 2*WB);
  unsigned short* Wob = (unsigned short*)(ws + 3*XB + 3*WB);
  unsigned short* Qb  = (unsigned short*)(ws + 3*XB + 4*WB);
  unsigned short* Kb  = (unsigned short*)(ws + 4*XB + 4*WB);
  unsigned short* Vtg = (unsigned short*)(ws + 5*XB + 4*WB);  // V^T (e-major)
  unsigned short* Ob  = (unsigned short*)(ws + 6*XB + 4*WB);  // ends at 64 MiB

  // one fused convert launch: (3*2^19 + 4*2^17)/256 = 8192 blocks
  cvt_all<<<8192, 256, 0, stream>>>(q_in, k_in, v_in, Wq, Wk, Wv, Wo,
                                    Xq, Xk, Xv, Wqb, Wkb, Wvb, Wob);

  const float qscale = 0.125f * 1.44269504088896340736f;  // scale * log2(e)
  gemm_qkv<<<dim3(256, 1, 3), 512, 0, stream>>>(Xq, Xk, Xv, Wqb, Wkb, Wvb,
                                                bq, bk, bv, Qb, Kb, Vtg, qscale);

  attn_fwd7<<<256, 512, 0, stream>>>(Qb, Kb, Vtg, Ob);   // 8 qt x 32 bh, xcd-swizzled

  dim3 ogrid(E_DIM/64, M_ROWS/128);        // 512 blocks
  gemm_o<<<ogrid, 256, 0, stream>>>(Ob, Wob, bo, (float*)d_out);
}

// Round 17
// 121.029 us; speedup vs baseline: 1.4456x; 1.0073x over previous
//
#include <hip/hip_runtime.h>
#include <stdint.h>

#define E_DIM 1024
#define N_HEADS 16
#define HEAD_D 64
#define BATCH 2
#define SEQ 2048
#define M_ROWS (BATCH*SEQ)   // 4096

typedef __attribute__((ext_vector_type(8))) short short8;
typedef __attribute__((ext_vector_type(4))) short short4_t;
typedef __attribute__((ext_vector_type(4))) float f32x4;
typedef __attribute__((ext_vector_type(4))) int i32x4;
typedef __attribute__((ext_vector_type(2))) int i32x2;

__device__ __forceinline__ unsigned short f2bf(float f) {
  uint32_t u = __float_as_uint(f);
  u += 0x7FFFu + ((u >> 16) & 1u);   // RTNE
  return (unsigned short)(u >> 16);
}

// async global->LDS, 16B per lane; LDS dest = wave-uniform base + lane*16
__device__ __forceinline__ void gload_lds16(const void* g, void* l) {
  __builtin_amdgcn_global_load_lds(
      (const __attribute__((address_space(1))) uint32_t*)(uintptr_t)g,
      (__attribute__((address_space(3))) uint32_t*)(uint32_t)(uintptr_t)l,
      16, 0, 0);
}

__device__ __forceinline__ int cvtpk(float lo, float hi) {
  int r;
  asm("v_cvt_pk_bf16_f32 %0, %1, %2" : "=v"(r) : "v"(lo), "v"(hi));
  return r;
}

__device__ __forceinline__ void cvt_body(const float* __restrict__ src,
                                         unsigned short* __restrict__ dst, int i) {
  f32x4 a = ((const f32x4*)src)[2*i];
  f32x4 b = ((const f32x4*)src)[2*i + 1];
  union { unsigned short us[8]; i32x4 v; } o;
  o.us[0] = f2bf(a[0]); o.us[1] = f2bf(a[1]);
  o.us[2] = f2bf(a[2]); o.us[3] = f2bf(a[3]);
  o.us[4] = f2bf(b[0]); o.us[5] = f2bf(b[1]);
  o.us[6] = f2bf(b[2]); o.us[7] = f2bf(b[3]);
  ((i32x4*)dst)[i] = o.v;
}

// All 7 f32->bf16 converts in ONE launch (R15-verified).
__global__ void cvt_all(const float* __restrict__ x0, const float* __restrict__ x1,
                        const float* __restrict__ x2,
                        const float* __restrict__ w0, const float* __restrict__ w1,
                        const float* __restrict__ w2, const float* __restrict__ w3,
                        unsigned short* __restrict__ dx0, unsigned short* __restrict__ dx1,
                        unsigned short* __restrict__ dx2,
                        unsigned short* __restrict__ dw0, unsigned short* __restrict__ dw1,
                        unsigned short* __restrict__ dw2, unsigned short* __restrict__ dw3) {
  const int i = blockIdx.x * blockDim.x + threadIdx.x;
  constexpr int NX8 = M_ROWS * E_DIM / 8;   // 2^19
  constexpr int NW8 = E_DIM * E_DIM / 8;    // 2^17
  if (i < 3 * NX8) {
    const int r = i >> 19, off = i & (NX8 - 1);
    const float* s = (r == 0) ? x0 : (r == 1) ? x1 : x2;
    unsigned short* d = (r == 0) ? dx0 : (r == 1) ? dx1 : dx2;
    cvt_body(s, d, off);
  } else {
    const int j = i - 3 * NX8;
    const int r = j >> 17, off = j & (NW8 - 1);
    const float* s = (r == 0) ? w0 : (r == 1) ? w1 : (r == 2) ? w2 : w3;
    unsigned short* d = (r == 0) ? dw0 : (r == 1) ? dw1 : (r == 2) ? dw2 : dw3;
    cvt_body(s, d, off);
  }
}

// ---------------------------------------------------------------------------
// 8-wave GEMM body (R15/R16-verified), runtime epilogue.
// ---------------------------------------------------------------------------
__device__ __forceinline__ void gemm_body_rt8(const unsigned short* __restrict__ A,
                                              const unsigned short* __restrict__ Bm,
                                              const float* __restrict__ bias,
                                              unsigned short* __restrict__ Cout,
                                              float scale, int bx, int by,
                                              int Nstr, bool brow) {
  constexpr int BM = 128, BN = 128, BK = 64, K = E_DIM;
  __shared__ __attribute__((aligned(16))) unsigned short Al[2][BM*BK];
  __shared__ __attribute__((aligned(16))) unsigned short Bl[2][BN*BK];
  const int tid  = threadIdx.x;
  const int lane = tid & 63, w = tid >> 6;
  const int wm = w >> 2, wn = w & 3;
  const int l15 = lane & 15, l4 = lane >> 4, l7 = lane & 7;
  const int m0 = by * BM, n0 = bx * BN;
  const int jr = lane >> 3, jc = lane & 7;
  const int kcg = jc ^ jr;

#define GSTAGE(KT, BUF)                                                        \
  do {                                                                         \
    _Pragma("unroll")                                                          \
    for (int t = 0; t < 2; ++t) {                                              \
      int ia = w*2 + t;                                                        \
      const char* src = (const char*)A +                                       \
          ((size_t)(m0 + ia*8 + jr)*K + (KT))*2 + (kcg << 4);                  \
      gload_lds16(src, (char*)Al[BUF] + ia*1024);                              \
    }                                                                          \
    _Pragma("unroll")                                                          \
    for (int t = 0; t < 2; ++t) {                                              \
      int ib = w*2 + t;                                                        \
      const char* src = (const char*)Bm +                                      \
          ((size_t)(n0 + ib*8 + jr)*K + (KT))*2 + (kcg << 4);                  \
      gload_lds16(src, (char*)Bl[BUF] + ib*1024);                              \
    }                                                                          \
  } while (0)

  f32x4 zero = {0.f, 0.f, 0.f, 0.f};
  f32x4 acc[4][2];
  for (int i = 0; i < 4; ++i) for (int j = 0; j < 2; ++j) acc[i][j] = zero;

  GSTAGE(0, 0);
  __syncthreads();

  int cur = 0;
  const int NKT = K / BK;
  for (int kt = 0; kt < NKT; ++kt) {
    if (kt + 1 < NKT) GSTAGE((kt + 1) * BK, cur ^ 1);

#pragma unroll
    for (int ks = 0; ks < 2; ++ks) {
      const int sw = ((ks*4 + l4) ^ l7) << 4;
      short8 af[4], bf[2];
#pragma unroll
      for (int mf = 0; mf < 4; ++mf)
        af[mf] = *(const short8*)((const char*)Al[cur] + (wm*64 + mf*16 + l15)*128 + sw);
#pragma unroll
      for (int nf = 0; nf < 2; ++nf)
        bf[nf] = *(const short8*)((const char*)Bl[cur] + (wn*32 + nf*16 + l15)*128 + sw);
      __builtin_amdgcn_s_setprio(1);
#pragma unroll
      for (int mf = 0; mf < 4; ++mf)
#pragma unroll
        for (int nf = 0; nf < 2; ++nf)
          acc[mf][nf] = __builtin_amdgcn_mfma_f32_16x16x32_bf16(
              af[mf], bf[nf], acc[mf][nf], 0, 0, 0);
      __builtin_amdgcn_s_setprio(0);
    }

    __syncthreads();
    cur ^= 1;
  }
#undef GSTAGE

#pragma unroll
  for (int nf = 0; nf < 2; ++nf) {
    const int col = n0 + wn*32 + nf*16 + l15;
    const float bcol = brow ? 0.f : bias[col];
#pragma unroll
    for (int mf = 0; mf < 4; ++mf) {
      const int rowb = m0 + wm*64 + mf*16 + l4*4;
#pragma unroll
      for (int r = 0; r < 4; ++r) {
        const float bv = brow ? bias[rowb + r] : bcol;
        float v = (acc[mf][nf][r] + bv) * scale;
        Cout[(size_t)(rowb + r)*Nstr + col] = f2bf(v);
      }
    }
  }
}

// Fused Q/K/V projections, 128x128 tiles: grid (256, 1, 3).
__global__ __launch_bounds__(512, 4)
void gemm_qkv(const unsigned short* __restrict__ Xq, const unsigned short* __restrict__ Xk,
              const unsigned short* __restrict__ Xv,
              const unsigned short* __restrict__ Wq, const unsigned short* __restrict__ Wk,
              const unsigned short* __restrict__ Wv,
              const float* __restrict__ bq, const float* __restrict__ bk,
              const float* __restrict__ bv,
              unsigned short* __restrict__ Qb, unsigned short* __restrict__ Kb,
              unsigned short* __restrict__ Vt, float scale0) {
  const int z = blockIdx.z;
  const int idx = blockIdx.x;
  if (z == 2) {
    gemm_body_rt8(Wv, Xv, bv, Vt, 1.0f, idx & 31, idx >> 5, M_ROWS, true);
  } else {
    const unsigned short* A  = (z == 0) ? Xq : Xk;
    const unsigned short* Bm = (z == 0) ? Wq : Wk;
    const float* bias        = (z == 0) ? bq : bk;
    unsigned short* C        = (z == 0) ? Qb : Kb;
    const float scale        = (z == 0) ? scale0 : 1.0f;
    gemm_body_rt8(A, Bm, bias, C, scale, idx & 7, idx >> 3, E_DIM, false);
  }
}

// Output projection, f32 out to d_out (R8-verified 128x64 / 256 threads).
__global__ __launch_bounds__(256, 2)
void gemm_o(const unsigned short* __restrict__ A, const unsigned short* __restrict__ Bm,
            const float* __restrict__ bias, float* __restrict__ Cout) {
  constexpr int BM = 128, BN = 64, BK = 64, K = E_DIM, N = E_DIM;
  __shared__ __attribute__((aligned(16))) unsigned short Al[2][BM*BK];
  __shared__ __attribute__((aligned(16))) unsigned short Bl[2][BN*BK];
  const int tid  = threadIdx.x;
  const int lane = tid & 63, w = tid >> 6;
  const int wm = w >> 1, wn = w & 1;
  const int l15 = lane & 15, l4 = lane >> 4, l7 = lane & 7;
  const int m0 = blockIdx.y * BM, n0 = blockIdx.x * BN;
  const int jr = lane >> 3, jc = lane & 7;
  const int kcg = jc ^ jr;

#define GSTAGE(KT, BUF)                                                        \
  do {                                                                         \
    _Pragma("unroll")                                                          \
    for (int t = 0; t < 4; ++t) {                                              \
      int ia = w*4 + t;                                                        \
      const char* src = (const char*)A +                                       \
          ((size_t)(m0 + ia*8 + jr)*K + (KT))*2 + (kcg << 4);                  \
      gload_lds16(src, (char*)Al[BUF] + ia*1024);                              \
    }                                                                          \
    _Pragma("unroll")                                                          \
    for (int t = 0; t < 2; ++t) {                                              \
      int ib = w*2 + t;                                                        \
      const char* src = (const char*)Bm +                                      \
          ((size_t)(n0 + ib*8 + jr)*K + (KT))*2 + (kcg << 4);                  \
      gload_lds16(src, (char*)Bl[BUF] + ib*1024);                              \
    }                                                                          \
  } while (0)

  f32x4 zero = {0.f, 0.f, 0.f, 0.f};
  f32x4 acc[4][2];
  for (int i = 0; i < 4; ++i) for (int j = 0; j < 2; ++j) acc[i][j] = zero;

  GSTAGE(0, 0);
  __syncthreads();

  int cur = 0;
  const int NKT = K / BK;
  for (int kt = 0; kt < NKT; ++kt) {
    if (kt + 1 < NKT) GSTAGE((kt + 1) * BK, cur ^ 1);
#pragma unroll
    for (int ks = 0; ks < 2; ++ks) {
      const int sw = ((ks*4 + l4) ^ l7) << 4;
      short8 af[4], bf[2];
#pragma unroll
      for (int mf = 0; mf < 4; ++mf)
        af[mf] = *(const short8*)((const char*)Al[cur] + (wm*64 + mf*16 + l15)*128 + sw);
#pragma unroll
      for (int nf = 0; nf < 2; ++nf)
        bf[nf] = *(const short8*)((const char*)Bl[cur] + (wn*32 + nf*16 + l15)*128 + sw);
      __builtin_amdgcn_s_setprio(1);
#pragma unroll
      for (int mf = 0; mf < 4; ++mf)
#pragma unroll
        for (int nf = 0; nf < 2; ++nf)
          acc[mf][nf] = __builtin_amdgcn_mfma_f32_16x16x32_bf16(
              af[mf], bf[nf], acc[mf][nf], 0, 0, 0);
      __builtin_amdgcn_s_setprio(0);
    }
    __syncthreads();
    cur ^= 1;
  }
#undef GSTAGE

#pragma unroll
  for (int nf = 0; nf < 2; ++nf) {
    const int col = n0 + wn*32 + nf*16 + l15;
    const float bv = bias[col];
#pragma unroll
    for (int mf = 0; mf < 4; ++mf) {
      const int rowb = m0 + wm*64 + mf*16 + l4*4;
#pragma unroll
      for (int r = 0; r < 4; ++r)
        Cout[(size_t)(rowb + r)*N + col] = acc[mf][nf][r] + bv;
    }
  }
}

// ---------------------------------------------------------------------------
// Flash attention v8: R16-verified per-tile compute (8 waves x 2 q-groups x
// 16 rows = 256-q tile, shared K/V frags), now with a 4-buffer ring and TWO
// tiles per barrier: stage pair {2p+2, 2p+3} -> bufs {(2p+2)&3, (2p+3)&3},
// compute tiles 2p and 2p+1, ONE barrier. Halves barrier count (32 -> 16)
// and lets tile 2p+1's MFMAs overlap tile 2p's softmax VALU.
// LDS: K 4x8KB + V 4x8KB + P 16KB = 80KB (grid 256 = 1 block/CU regardless).
// ---------------------------------------------------------------------------
__global__ __launch_bounds__(512, 2)
void attn_fwd8(const unsigned short* __restrict__ Q,
               const unsigned short* __restrict__ Kg,
               const unsigned short* __restrict__ Vt_g,
               unsigned short* __restrict__ O) {
  __shared__ __attribute__((aligned(16))) unsigned short Kl[4][4096];
  __shared__ __attribute__((aligned(16))) unsigned short Vl[4][4096];
  __shared__ __attribute__((aligned(16))) unsigned short Pl[8][2][1024];

  const int tid = threadIdx.x;
  const int l = tid & 63, w = tid >> 6;
  const int l15 = l & 15, l4 = l >> 4, l7 = l & 7;

  // XCD-aware bijective decode: 256 blocks = 8 qt x 32 bh; XCD x gets bh 4x..4x+3
  const int id = blockIdx.x;
  const int bh = (id & 7) * 4 + ((id >> 3) & 3);
  const int qt = id >> 5;                       // 0..7
  const int b = bh >> 4, h = bh & 15;
  const size_t bS = (size_t)b * SEQ;
  const int qw = qt * 256 + w * 32;             // wave's q base (32 rows)

  // Q fragments, 2 groups: lane holds Q[q = qw + g*16 + l15][e = ks*32+l4*8+j]
  short8 qf[2][2];
#pragma unroll
  for (int g = 0; g < 2; ++g) {
    const char* qp = (const char*)Q + ((bS + qw + g*16 + l15) * E_DIM + h * 64) * 2;
    qf[g][0] = *(const short8*)(qp + l4 * 16);
    qf[g][1] = *(const short8*)(qp + 64 + l4 * 16);
  }

  f32x4 zero = {0.f, 0.f, 0.f, 0.f};
  f32x4 oacc[2][4];                              // O^T: d=df*16+l4*4+r, q=l15
#pragma unroll
  for (int g = 0; g < 2; ++g)
#pragma unroll
    for (int i = 0; i < 4; ++i) oacc[g][i] = zero;
  float mrow[2] = {-1e30f, -1e30f}, lrow[2] = {0.f, 0.f};

  // staging maps (R14-verified)
  const int krow = l >> 3;                       // 0..7
  const int kcg  = (l & 7) ^ krow;               // inverse-swizzled source octet
  const char* vt_base = (const char*)Vt_g +
      ((size_t)(h * 64 + 8 * w + krow) * M_ROWS + bS) * 2 + (kcg << 4);

#define KSTAGE(KT, BUF)                                                        \
  gload_lds16((const char*)Kg +                                                \
                  ((bS + (size_t)(KT)*64 + 8*w + krow) * E_DIM + h*64 + kcg*8)*2, \
              (char*)Kl[BUF] + w * 1024)

#define VSTAGE(KT, BUF)                                                        \
  gload_lds16(vt_base + (size_t)(KT) * 128, (char*)Vl[BUF] + w * 1024)

  // one KV tile: QK^T + online softmax + P round-trip + PV (R16-verified body)
  auto tile_step = [&](int buf) {
    // ---- K fragments ONCE (shared by both q-groups) ----
    short8 kf[8];
    {
      const char* kb = (const char*)Kl[buf];
#pragma unroll
      for (int nf = 0; nf < 4; ++nf) {
        const char* rowb = kb + (nf * 16 + l15) * 128;
        kf[nf*2]     = *(const short8*)(rowb + ((l4 ^ l7) << 4));
        kf[nf*2 + 1] = *(const short8*)(rowb + (((4 + l4) ^ l7) << 4));
      }
    }

    short8 pf[2][2];
#pragma unroll
    for (int g = 0; g < 2; ++g) {
      f32x4 s[4];
      __builtin_amdgcn_s_setprio(1);
#pragma unroll
      for (int nf = 0; nf < 4; ++nf) {
        f32x4 z = zero;
        z = __builtin_amdgcn_mfma_f32_16x16x32_bf16(kf[nf*2],     qf[g][0], z, 0, 0, 0);
        z = __builtin_amdgcn_mfma_f32_16x16x32_bf16(kf[nf*2 + 1], qf[g][1], z, 0, 0, 0);
        s[nf] = z;
      }
      __builtin_amdgcn_s_setprio(0);

      float mx = s[0][0];
#pragma unroll
      for (int nf = 0; nf < 4; ++nf)
#pragma unroll
        for (int r = 0; r < 4; ++r) mx = fmaxf(mx, s[nf][r]);
      mx = fmaxf(mx, __shfl_xor(mx, 16));
      mx = fmaxf(mx, __shfl_xor(mx, 32));
      const float mnew = fmaxf(mrow[g], mx);
      const float fac = __builtin_amdgcn_exp2f(mrow[g] - mnew);
      mrow[g] = mnew;

      float pv[4][4];
      float rs = 0.f;
#pragma unroll
      for (int nf = 0; nf < 4; ++nf)
#pragma unroll
        for (int r = 0; r < 4; ++r) {
          float p = __builtin_amdgcn_exp2f(s[nf][r] - mnew);
          pv[nf][r] = p;
          rs += p;
        }
      rs += __shfl_xor(rs, 16);
      rs += __shfl_xor(rs, 32);
      lrow[g] = lrow[g] * fac + rs;

#pragma unroll
      for (int df = 0; df < 4; ++df)
#pragma unroll
        for (int r = 0; r < 4; ++r) oacc[g][df][r] *= fac;

      // P -> per-(wave,group) LDS, packed b64, chunk-XOR swizzle by q(&7)=l7
      char* pw = (char*)&Pl[w][g][0];
#pragma unroll
      for (int nf = 0; nf < 4; ++nf) {
        const int c = nf * 2 + (l4 >> 1);
        i32x2 pk;
        pk.x = cvtpk(pv[nf][0], pv[nf][1]);
        pk.y = cvtpk(pv[nf][2], pv[nf][3]);
        *(i32x2*)(pw + l15 * 128 + ((c ^ l7) << 4) + ((l4 & 1) << 3)) = pk;
      }
      pf[g][0] = *(const short8*)(pw + l15 * 128 + ((l4 ^ l7) << 4));
      pf[g][1] = *(const short8*)(pw + l15 * 128 + (((4 + l4) ^ l7) << 4));
    }

    // ---- V fragments ONCE; PV for both groups ----
    {
      const char* vbuf = (const char*)Vl[buf];
      __builtin_amdgcn_s_setprio(1);
#pragma unroll
      for (int df = 0; df < 4; ++df) {
        const char* rowb = vbuf + (df * 16 + l15) * 128;
        short8 v0 = *(const short8*)(rowb + ((l4 ^ l7) << 4));
        short8 v1 = *(const short8*)(rowb + (((4 + l4) ^ l7) << 4));
#pragma unroll
        for (int g = 0; g < 2; ++g) {
          oacc[g][df] = __builtin_amdgcn_mfma_f32_16x16x32_bf16(v0, pf[g][0], oacc[g][df], 0, 0, 0);
          oacc[g][df] = __builtin_amdgcn_mfma_f32_16x16x32_bf16(v1, pf[g][1], oacc[g][df], 0, 0, 0);
        }
      }
      __builtin_amdgcn_s_setprio(0);
    }
  };

  // prologue: tiles 0,1 -> bufs 0,1
  KSTAGE(0, 0); VSTAGE(0, 0);
  KSTAGE(1, 1); VSTAGE(1, 1);
  __syncthreads();

  constexpr int NP = SEQ / 128;                 // 16 tile-pairs
  for (int p = 0; p < NP; ++p) {
    const int t0 = 2 * p;
    if (p + 1 < NP) {                           // stage next pair into other bufs
      KSTAGE(t0 + 2, (t0 + 2) & 3); VSTAGE(t0 + 2, (t0 + 2) & 3);
      KSTAGE(t0 + 3, (t0 + 3) & 3); VSTAGE(t0 + 3, (t0 + 3) & 3);
    }
    tile_step(t0 & 3);
    tile_step((t0 + 1) & 3);
    __syncthreads();   // drains vmcnt+lgkmcnt: next pair staged, this pair free
  }
#undef KSTAGE
#undef VSTAGE

  // ---- epilogue: O[q = qw + g*16 + l15][d = df*16 + l4*4 + r] ----
#pragma unroll
  for (int g = 0; g < 2; ++g) {
    const float rinv = __builtin_amdgcn_rcpf(lrow[g]);
    unsigned short* orow = O + (bS + qw + g*16 + l15) * E_DIM + h * 64;
#pragma unroll
    for (int df = 0; df < 4; ++df) {
      short4_t o4;
#pragma unroll
      for (int r = 0; r < 4; ++r) o4[r] = (short)f2bf(oacc[g][df][r] * rinv);
      *(short4_t*)(orow + df * 16 + l4 * 4) = o4;
    }
  }
}

extern "C" void kernel_launch(void* const* d_in, const int* in_sizes, int n_in,
                              void* d_out, int out_size, void* d_ws, size_t ws_size,
                              hipStream_t stream) {
  const float* q_in = (const float*)d_in[0];
  const float* k_in = (const float*)d_in[1];
  const float* v_in = (const float*)d_in[2];
  const float* Wq = (const float*)d_in[3];
  const float* bq = (const float*)d_in[4];
  const float* Wk = (const float*)d_in[5];
  const float* bk = (const float*)d_in[6];
  const float* Wv = (const float*)d_in[7];
  const float* bv = (const float*)d_in[8];
  const float* Wo = (const float*)d_in[9];
  const float* bo = (const float*)d_in[10];

  char* ws = (char*)d_ws;
  const size_t XB = (size_t)M_ROWS * E_DIM * 2;   // 8 MiB
  const size_t WB = (size_t)E_DIM * E_DIM * 2;    // 2 MiB
  unsigned short* Xq  = (unsigned short*)(ws);
  unsigned short* Xk  = (unsigned short*)(ws + XB);
  unsigned short* Xv  = (unsigned short*)(ws + 2*XB);
  unsigned short* Wqb = (unsigned short*)(ws + 3*XB);
  unsigned short* Wkb = (unsigned short*)(ws + 3*XB + WB);
  unsigned short* Wvb = (unsigned short*)(ws + 3*XB + 2*WB);
  unsigned short* Wob = (unsigned short*)(ws + 3*XB + 3*WB);
  unsigned short* Qb  = (unsigned short*)(ws + 3*XB + 4*WB);
  unsigned short* Kb  = (unsigned short*)(ws + 4*XB + 4*WB);
  unsigned short* Vtg = (unsigned short*)(ws + 5*XB + 4*WB);  // V^T (e-major)
  unsigned short* Ob  = (unsigned short*)(ws + 6*XB + 4*WB);  // ends at 64 MiB

  // one fused convert launch: (3*2^19 + 4*2^17)/256 = 8192 blocks
  cvt_all<<<8192, 256, 0, stream>>>(q_in, k_in, v_in, Wq, Wk, Wv, Wo,
                                    Xq, Xk, Xv, Wqb, Wkb, Wvb, Wob);

  const float qscale = 0.125f * 1.44269504088896340736f;  // scale * log2(e)
  gemm_qkv<<<dim3(256, 1, 3), 512, 0, stream>>>(Xq, Xk, Xv, Wqb, Wkb, Wvb,
                                                bq, bk, bv, Qb, Kb, Vtg, qscale);

  attn_fwd8<<<256, 512, 0, stream>>>(Qb, Kb, Vtg, Ob);   // 8 qt x 32 bh, xcd-swizzled

  dim3 ogrid(E_DIM/64, M_ROWS/128);        // 512 blocks
  gemm_o<<<ogrid, 256, 0, stream>>>(Ob, Wob, bo, (float*)d_out);
}